// Round 5
// baseline (12398.113 us; speedup 1.0000x reference)
//
#include <hip/hip_runtime.h>
#include <math.h>

#define B_ 256
#define T_ 128
#define D_ 64
#define H_ 512
#define A_ 128
#define O_ 32

typedef __attribute__((ext_vector_type(8))) short short8;
typedef __attribute__((ext_vector_type(8))) unsigned short ushort8;
typedef __attribute__((ext_vector_type(4))) float floatx4;

__device__ __forceinline__ float sp_(float x) {
    return fmaxf(x, 0.f) + log1pf(expf(-fabsf(x)));
}
__device__ __forceinline__ float sigm_(float x) {
    return 1.f / (1.f + expf(-x));
}
__device__ __forceinline__ unsigned short f2bf_(float f) {
    unsigned int u = __float_as_uint(f);
    return (unsigned short)((u + 0x7FFFu + ((u >> 16) & 1u)) >> 16);
}
__device__ __forceinline__ float bf2f_(unsigned short u) {
    return __uint_as_float(((unsigned)u) << 16);
}

// ---------------- init: hpack = 0, barriers = 0 -----------------------------
__global__ void init_kernel(unsigned short* __restrict__ hpack,
                            unsigned* __restrict__ bar) {
    int i = blockIdx.x * 256 + threadIdx.x;
    if (i < B_ * H_) hpack[i] = 0;
    if (i < 256) bar[i] = 0u;
}

// -------- pack all weights into MFMA B-frag bf16 order ----------------------
// regions (ushort offsets): y:[0,786432) x:[786432,851968) c:[851968,983040)
//                           kv:[983040,1114112)
__global__ void pack_w_kernel(const float* __restrict__ W_gd,
                              const float* __restrict__ W_tau,
                              const float* __restrict__ Wk,
                              const float* __restrict__ Wv,
                              unsigned short* __restrict__ Wpack) {
    int gid = blockIdx.x * 256 + threadIdx.x;
    if (gid >= 1114112) return;
    int j = gid & 7;
    int l = (gid >> 3) & 63;
    int kpart = (l >> 4) * 8 + j;
    int npart = l & 15;
    float v;
    if (gid < 786432) {
        int f = gid >> 9;
        int s = f % 3;
        int rem = f / 3;
        int kb = rem & 15, ct = rem >> 4;
        int k = kb * 32 + kpart;
        int c = ct * 16 + npart;
        if (s == 0)      v = W_gd[(size_t)(D_ + k) * 1024 + c];
        else if (s == 1) v = W_gd[(size_t)(D_ + k) * 1024 + 512 + c];
        else             v = W_tau[(size_t)k * 512 + c];
    } else if (gid < 851968) {
        int r = gid - 786432;
        int f = r >> 9;
        int s = f & 1, kb = (f >> 1) & 1, ct = f >> 2;
        int k = kb * 32 + kpart;
        int c = ct * 16 + npart;
        v = W_gd[(size_t)k * 1024 + s * 512 + c];
    } else if (gid < 983040) {
        int r = gid - 851968;
        int f = r >> 9;
        int s = f & 1, kb = (f >> 1) & 3, ct = f >> 3;
        int k = kb * 32 + kpart;
        int c = ct * 16 + npart;
        v = W_gd[(size_t)(D_ + H_ + k) * 1024 + s * 512 + c];
    } else {
        int r = gid - 983040;
        int f = r >> 9;
        int kb = f & 15, c4 = f >> 4;
        int k = kb * 32 + kpart;
        int n = (c4 & 7) * 16 + npart;
        v = (c4 < 8) ? Wk[(size_t)k * A_ + n] : Wv[(size_t)k * A_ + n];
    }
    Wpack[gid] = f2bf_(v);
}

// ---------------- group barrier: 4 blocks, generation counter ---------------
__device__ __forceinline__ void gsync4(unsigned* barg) {
    __syncthreads();
    if (threadIdx.x == 0) {
        unsigned g = __hip_atomic_load(barg + 1, __ATOMIC_RELAXED,
                                       __HIP_MEMORY_SCOPE_AGENT);
        unsigned old = __hip_atomic_fetch_add(barg, 1u, __ATOMIC_ACQ_REL,
                                              __HIP_MEMORY_SCOPE_AGENT);
        if (old == 3u) {
            __hip_atomic_store(barg, 0u, __ATOMIC_RELAXED,
                               __HIP_MEMORY_SCOPE_AGENT);
            __hip_atomic_fetch_add(barg + 1, 1u, __ATOMIC_ACQ_REL,
                                   __HIP_MEMORY_SCOPE_AGENT);
        } else {
            while (__hip_atomic_load(barg + 1, __ATOMIC_RELAXED,
                                     __HIP_MEMORY_SCOPE_AGENT) == g) {
                __builtin_amdgcn_s_sleep(1);
            }
        }
    }
    __syncthreads();
    __builtin_amdgcn_fence(__ATOMIC_ACQUIRE, "agent");
}

struct P {
    const float *x, *dts, *Wq, *bq, *bk, *bv, *b_gd, *b_tau, *gleak, *cm,
        *W_fc, *b_fc;
    float *h, *ctx, *out;
    unsigned short *Kh, *Vh;  // K: [B][T][A] bf16 ; V: [B][A][T] bf16
    const unsigned short *Wy, *Wx, *Wc, *Wkv;
    unsigned short *hpack, *yapack, *ybpack;
    unsigned* bar;
};

__device__ __forceinline__ void gemm3(const short8 (&wg)[16],
                                      const short8 (&wd)[16],
                                      const short8 (&wt)[16],
                                      const short8* Ap, int m_tile, int lane,
                                      floatx4& ag, floatx4& ad, floatx4& at) {
    #pragma unroll
    for (int kb = 0; kb < 16; ++kb) {
        short8 a = Ap[(m_tile * 16 + kb) * 64 + lane];
        ag = __builtin_amdgcn_mfma_f32_16x16x32_bf16(a, wg[kb], ag, 0, 0, 0);
        ad = __builtin_amdgcn_mfma_f32_16x16x32_bf16(a, wd[kb], ad, 0, 0, 0);
        at = __builtin_amdgcn_mfma_f32_16x16x32_bf16(a, wt[kb], at, 0, 0, 0);
    }
}

__global__ __launch_bounds__(512, 2) void fused_kernel(P p) {
    const int tid = threadIdx.x;
    const int bid = blockIdx.x;
    const int lane = tid & 63;
    const int wave = tid >> 6;            // 0..7
    const int g = bid & 15;               // group: 4 blocks share bid%8 -> XCD
    const int j = bid >> 4;               // block within group 0..3
    const int ct = j * 8 + wave;          // channel strip 0..31
    const int m_tile = g;                 // batch tile (16 rows)
    unsigned* barg = p.bar + g * 16;

    __shared__ float WqL[D_ * 129];
    __shared__ float xs4[4][D_];
    __shared__ float q4[4][A_];
    __shared__ float sc4[4][T_];
    __shared__ float red[4][2];

    // persistent y-part B-fragments (192 VGPRs)
    short8 wg[16], wd[16], wt[16];
    {
        const short8* Wy8 = (const short8*)p.Wy;
        #pragma unroll
        for (int kb = 0; kb < 16; ++kb) {
            wg[kb] = Wy8[((ct * 16 + kb) * 3 + 0) * 64 + lane];
            wd[kb] = Wy8[((ct * 16 + kb) * 3 + 1) * 64 + lane];
            wt[kb] = Wy8[((ct * 16 + kb) * 3 + 2) * 64 + lane];
        }
    }
    const int quad = lane >> 4;
    const int c = ct * 16 + (lane & 15);
    const float btau = p.b_tau[c];
    const float lk = sp_(p.cm[c]) + sp_(p.gleak[c]) + 1e-6f;
    const float bgd_g = p.b_gd[c];
    const float bgd_d = p.b_gd[512 + c];
    const int lane_p = ((c >> 3) & 3) * 16;
    const int pbase = (m_tile * 16 + (c >> 5)) * 512 + (c & 7);

    // attention assignment: sub-row within block
    const int sub = tid >> 7;             // 0..3
    const int tl = tid & 127;
    const int r = g * 16 + j * 4 + sub;   // this block's attention rows

    // kv constants (phase F active for ct<16)
    const int a_col = (ct & 7) * 16 + (lane & 15);
    float kv_bias = 0.f;
    if (ct < 16) kv_bias = (ct < 8 ? p.bk : p.bv)[a_col];

    // Wq -> LDS (stride 129 to break bank alignment)
    for (int i = tid; i < D_ * A_; i += 512) {
        int d = i >> 7, a = i & 127;
        WqL[d * 129 + a] = p.Wq[i];
    }

    floatx4 hreg = {0.f, 0.f, 0.f, 0.f};
    floatx4 rk1, rk2, rk3, baseg, based, ycur, dt4;

    const short8* Wx8 = (const short8*)p.Wx;
    const short8* Wc8 = (const short8*)p.Wc;
    const short8* Wkv8 = (const short8*)p.Wkv;
    const short8* Ahp = (const short8*)p.hpack;
    const short8* Aya = (const short8*)p.yapack;
    const short8* Ayb = (const short8*)p.ybpack;

    __syncthreads();  // WqL ready

    for (int t = 0; t < T_; ++t) {
        // ---------- phase A: attention for 4 rows (128 threads each) --------
        {
            if (tl < 16)
                ((float4*)xs4[sub])[tl] =
                    ((const float4*)&p.x[(r * T_ + t) * D_])[tl];
            __syncthreads();
            float qa = p.bq[tl];
            #pragma unroll 8
            for (int d = 0; d < D_; ++d) qa += xs4[sub][d] * WqL[d * 129 + tl];
            q4[sub][tl] = qa;
            __syncthreads();
            if (t == 0) {
                p.ctx[r * A_ + tl] = 0.f;
            } else {
                const float rscale = 0.08838834764831845f;  // 1/sqrt(128)
                const int grp = tl >> 4, ln = tl & 15;
                float qv[8];
                #pragma unroll
                for (int i = 0; i < 8; ++i) qv[i] = q4[sub][ln * 8 + i];
                for (int s = grp; s < t; s += 8) {
                    ushort8 k8 = *((const ushort8*)(p.Kh +
                                     (size_t)(r * T_ + s) * A_) + ln);
                    float a2 = 0.f;
                    #pragma unroll
                    for (int i = 0; i < 8; ++i) a2 += bf2f_(k8[i]) * qv[i];
                    #pragma unroll
                    for (int off = 8; off > 0; off >>= 1)
                        a2 += __shfl_xor(a2, off, 16);
                    if (ln == 0) sc4[sub][s] = a2 * rscale;
                }
                __syncthreads();
                float mloc = -1e30f;
                for (int s = tl; s < t; s += 128) mloc = fmaxf(mloc, sc4[sub][s]);
                #pragma unroll
                for (int off = 32; off > 0; off >>= 1)
                    mloc = fmaxf(mloc, __shfl_xor(mloc, off, 64));
                if (lane == 0) red[sub][wave & 1] = mloc;
                __syncthreads();
                float m = fmaxf(red[sub][0], red[sub][1]);
                float ssum = 0.f;
                for (int s = tl; s < t; s += 128) {
                    float e = expf(sc4[sub][s] - m);
                    sc4[sub][s] = e;
                    ssum += e;
                }
                #pragma unroll
                for (int off = 32; off > 0; off >>= 1)
                    ssum += __shfl_xor(ssum, off, 64);
                __syncthreads();
                if (lane == 0) red[sub][wave & 1] = ssum;
                __syncthreads();
                float rs = 1.f / (red[sub][0] + red[sub][1]);
                // ctx: V transposed [r][a][T], ushort8 = 8 steps per load
                const unsigned short* Vrow = p.Vh + (size_t)(r * A_ + tl) * T_;
                float ca0 = 0.f, ca1 = 0.f;
                int s0 = 0;
                for (; s0 + 16 <= t; s0 += 16) {
                    ushort8 v0 = *(const ushort8*)(Vrow + s0);
                    ushort8 v1 = *(const ushort8*)(Vrow + s0 + 8);
                    #pragma unroll
                    for (int i = 0; i < 8; ++i) {
                        ca0 += sc4[sub][s0 + i] * bf2f_(v0[i]);
                        ca1 += sc4[sub][s0 + 8 + i] * bf2f_(v1[i]);
                    }
                }
                if (s0 + 8 <= t) {
                    ushort8 v0 = *(const ushort8*)(Vrow + s0);
                    #pragma unroll
                    for (int i = 0; i < 8; ++i)
                        ca0 += sc4[sub][s0 + i] * bf2f_(v0[i]);
                    s0 += 8;
                }
                for (; s0 < t; ++s0) ca0 += sc4[sub][s0] * bf2f_(Vrow[s0]);
                p.ctx[r * A_ + tl] = (ca0 + ca1) * rs;
            }
        }
        gsync4(barg);

        // ---------- phase B: stage1 + base fold (x/ctx MFMA) ----------
        {
            const int mrow = lane & 15;
            const int kq = lane >> 4;
            #pragma unroll
            for (int i = 0; i < 4; ++i)
                dt4[i] = p.dts[(m_tile * 16 + quad * 4 + i) * T_ + t];

            const float4* xrow =
                (const float4*)&p.x[((m_tile * 16 + mrow) * T_ + t) * D_];
            const float4* crow =
                (const float4*)&p.ctx[(m_tile * 16 + mrow) * A_];
            floatx4 bg = {0.f, 0.f, 0.f, 0.f};
            floatx4 bd = {0.f, 0.f, 0.f, 0.f};
            #pragma unroll
            for (int kb = 0; kb < 2; ++kb) {
                float4 u = xrow[kb * 8 + kq * 2], v = xrow[kb * 8 + kq * 2 + 1];
                short8 ax;
                ax[0] = (short)f2bf_(u.x); ax[1] = (short)f2bf_(u.y);
                ax[2] = (short)f2bf_(u.z); ax[3] = (short)f2bf_(u.w);
                ax[4] = (short)f2bf_(v.x); ax[5] = (short)f2bf_(v.y);
                ax[6] = (short)f2bf_(v.z); ax[7] = (short)f2bf_(v.w);
                bg = __builtin_amdgcn_mfma_f32_16x16x32_bf16(
                    ax, Wx8[((ct * 2 + kb) * 2 + 0) * 64 + lane], bg, 0, 0, 0);
                bd = __builtin_amdgcn_mfma_f32_16x16x32_bf16(
                    ax, Wx8[((ct * 2 + kb) * 2 + 1) * 64 + lane], bd, 0, 0, 0);
            }
            #pragma unroll
            for (int kb = 0; kb < 4; ++kb) {
                float4 u = crow[kb * 8 + kq * 2], v = crow[kb * 8 + kq * 2 + 1];
                short8 ac;
                ac[0] = (short)f2bf_(u.x); ac[1] = (short)f2bf_(u.y);
                ac[2] = (short)f2bf_(u.z); ac[3] = (short)f2bf_(u.w);
                ac[4] = (short)f2bf_(v.x); ac[5] = (short)f2bf_(v.y);
                ac[6] = (short)f2bf_(v.z); ac[7] = (short)f2bf_(v.w);
                bg = __builtin_amdgcn_mfma_f32_16x16x32_bf16(
                    ac, Wc8[((ct * 4 + kb) * 2 + 0) * 64 + lane], bg, 0, 0, 0);
                bd = __builtin_amdgcn_mfma_f32_16x16x32_bf16(
                    ac, Wc8[((ct * 4 + kb) * 2 + 1) * 64 + lane], bd, 0, 0, 0);
            }
            floatx4 ag = {0.f, 0.f, 0.f, 0.f};
            floatx4 ad = {0.f, 0.f, 0.f, 0.f};
            floatx4 at = {0.f, 0.f, 0.f, 0.f};
            gemm3(wg, wd, wt, Ahp, m_tile, lane, ag, ad, at);
            #pragma unroll
            for (int i = 0; i < 4; ++i) {
                baseg[i] = bg[i] + bgd_g;
                based[i] = bd[i] + bgd_d;
                float gate = ag[i] + baseg[i];
                float dyn = ad[i] + based[i];
                float tau = sp_(at[i] + btau);
                float ki = (sigm_(gate) * tanhf(dyn) - hreg[i]) / (tau + lk);
                rk1[i] = ki;
                float yn = hreg[i] + dt4[i] * ki * (1.f / 3.f);
                ycur[i] = yn;
                p.yapack[pbase + (lane_p + (quad * 4 + i)) * 8] = f2bf_(yn);
            }
        }
        gsync4(barg);

        // ---------- stage 2 ----------
        {
            floatx4 ag = {0.f, 0.f, 0.f, 0.f};
            floatx4 ad = {0.f, 0.f, 0.f, 0.f};
            floatx4 at = {0.f, 0.f, 0.f, 0.f};
            gemm3(wg, wd, wt, Aya, m_tile, lane, ag, ad, at);
            #pragma unroll
            for (int i = 0; i < 4; ++i) {
                float gate = ag[i] + baseg[i];
                float dyn = ad[i] + based[i];
                float tau = sp_(at[i] + btau);
                float ki = (sigm_(gate) * tanhf(dyn) - ycur[i]) / (tau + lk);
                rk2[i] = ki;
                float yn = hreg[i] + dt4[i] * (ki - rk1[i] * (1.f / 3.f));
                ycur[i] = yn;
                p.ybpack[pbase + (lane_p + (quad * 4 + i)) * 8] = f2bf_(yn);
            }
        }
        gsync4(barg);

        // ---------- stage 3 ----------
        {
            floatx4 ag = {0.f, 0.f, 0.f, 0.f};
            floatx4 ad = {0.f, 0.f, 0.f, 0.f};
            floatx4 at = {0.f, 0.f, 0.f, 0.f};
            gemm3(wg, wd, wt, Ayb, m_tile, lane, ag, ad, at);
            #pragma unroll
            for (int i = 0; i < 4; ++i) {
                float gate = ag[i] + baseg[i];
                float dyn = ad[i] + based[i];
                float tau = sp_(at[i] + btau);
                float ki = (sigm_(gate) * tanhf(dyn) - ycur[i]) / (tau + lk);
                rk3[i] = ki;
                float yn = hreg[i] + dt4[i] * (rk1[i] - rk2[i] + ki);
                ycur[i] = yn;
                p.yapack[pbase + (lane_p + (quad * 4 + i)) * 8] = f2bf_(yn);
            }
        }
        gsync4(barg);

        // ---------- stage 4 ----------
        {
            floatx4 ag = {0.f, 0.f, 0.f, 0.f};
            floatx4 ad = {0.f, 0.f, 0.f, 0.f};
            floatx4 at = {0.f, 0.f, 0.f, 0.f};
            gemm3(wg, wd, wt, Aya, m_tile, lane, ag, ad, at);
            #pragma unroll
            for (int i = 0; i < 4; ++i) {
                float gate = ag[i] + baseg[i];
                float dyn = ad[i] + based[i];
                float tau = sp_(at[i] + btau);
                float ki = (sigm_(gate) * tanhf(dyn) - ycur[i]) / (tau + lk);
                hreg[i] = hreg[i] +
                          dt4[i] * (rk1[i] + 3.f * rk2[i] + 3.f * rk3[i] + ki) * 0.125f;
                p.hpack[pbase + (lane_p + (quad * 4 + i)) * 8] = f2bf_(hreg[i]);
            }
        }
        gsync4(barg);

        // ---------- phase F: K/V projection of h_next (bf16 out) ----------
        if (ct < 16) {
            floatx4 acc = {0.f, 0.f, 0.f, 0.f};
            #pragma unroll
            for (int kb = 0; kb < 16; ++kb) {
                short8 a = Ahp[(m_tile * 16 + kb) * 64 + lane];
                acc = __builtin_amdgcn_mfma_f32_16x16x32_bf16(
                    a, Wkv8[(ct * 16 + kb) * 64 + lane], acc, 0, 0, 0);
            }
            #pragma unroll
            for (int i = 0; i < 4; ++i) {
                int brow = m_tile * 16 + quad * 4 + i;
                float val = acc[i] + kv_bias;
                if (ct < 8)
                    p.Kh[(size_t)(brow * T_ + t) * A_ + a_col] = f2bf_(val);
                else
                    p.Vh[(size_t)(brow * A_ + a_col) * T_ + t] = f2bf_(val);
            }
        }
        gsync4(barg);
    }

    // ---------- write final h, then fc ----------
    #pragma unroll
    for (int i = 0; i < 4; ++i)
        p.h[(m_tile * 16 + quad * 4 + i) * H_ + c] = hreg[i];
    gsync4(barg);
    {
        const int o = tl & 31, ks = tl >> 5;  // ks 0..3
        float acc = 0.f;
        #pragma unroll 4
        for (int k = ks * 128; k < ks * 128 + 128; ++k)
            acc += p.h[r * H_ + k] * p.W_fc[k * O_ + o];
        sc4[sub][tl] = acc;
        __syncthreads();
        if (ks == 0)
            p.out[r * O_ + o] = acc + sc4[sub][o + 32] + sc4[sub][o + 64] +
                                sc4[sub][o + 96] + p.b_fc[o];
    }
}

extern "C" void kernel_launch(void* const* d_in, const int* in_sizes, int n_in,
                              void* d_out, int out_size, void* d_ws,
                              size_t ws_size, hipStream_t stream) {
    (void)in_sizes; (void)n_in; (void)out_size; (void)ws_size;
    P p;
    p.x = (const float*)d_in[0];
    p.dts = (const float*)d_in[1];
    p.Wq = (const float*)d_in[2];
    p.bq = (const float*)d_in[3];
    const float* Wk = (const float*)d_in[4];
    p.bk = (const float*)d_in[5];
    const float* Wv = (const float*)d_in[6];
    p.bv = (const float*)d_in[7];
    const float* W_gd = (const float*)d_in[8];
    p.b_gd = (const float*)d_in[9];
    const float* W_tau = (const float*)d_in[10];
    p.b_tau = (const float*)d_in[11];
    p.gleak = (const float*)d_in[12];
    p.cm = (const float*)d_in[13];
    p.W_fc = (const float*)d_in[14];
    p.b_fc = (const float*)d_in[15];
    p.out = (float*)d_out;

    float* ws = (float*)d_ws;
    p.h = ws;                            // B*H fp32
    p.ctx = p.h + B_ * H_;               // B*A fp32
    unsigned short* Wpack = (unsigned short*)(p.ctx + B_ * A_);
    p.Wy = Wpack;                        // 786432 ushorts
    p.Wx = Wpack + 786432;               // 65536
    p.Wc = Wpack + 851968;               // 131072
    p.Wkv = Wpack + 983040;              // 131072
    p.hpack = Wpack + 1114112;           // B*H ushorts
    p.yapack = p.hpack + B_ * H_;
    p.ybpack = p.yapack + B_ * H_;
    p.Kh = p.ybpack + B_ * H_;           // B*T*A bf16
    p.Vh = p.Kh + (size_t)B_ * T_ * A_;  // B*A*T bf16 (transposed)
    p.bar = (unsigned*)(p.Vh + (size_t)B_ * T_ * A_);  // 256 uints

    init_kernel<<<512, 256, 0, stream>>>(p.hpack, p.bar);
    pack_w_kernel<<<4352, 256, 0, stream>>>(W_gd, W_tau, Wk, Wv, Wpack);

    // 64 blocks x 512 threads (8 waves, <=256 VGPR each): 1 block/CU, 64 CUs,
    // all blocks trivially co-resident -> group barrier safe without
    // cooperative launch. Group = 4 blocks sharing bid%8 (XCD-local heuristic).
    fused_kernel<<<dim3(64), dim3(512), 0, stream>>>(p);
}

// Round 6
// 11995.444 us; speedup vs baseline: 1.0336x; 1.0336x over previous
//
#include <hip/hip_runtime.h>
#include <math.h>

#define B_ 256
#define T_ 128
#define D_ 64
#define H_ 512
#define A_ 128
#define O_ 32

typedef __attribute__((ext_vector_type(8))) short short8;
typedef __attribute__((ext_vector_type(8))) unsigned short ushort8;
typedef __attribute__((ext_vector_type(4))) float floatx4;

__device__ __forceinline__ float sp_(float x) {
    return fmaxf(x, 0.f) + log1pf(expf(-fabsf(x)));
}
__device__ __forceinline__ float sigm_(float x) {
    return 1.f / (1.f + expf(-x));
}
__device__ __forceinline__ unsigned short f2bf_(float f) {
    unsigned int u = __float_as_uint(f);
    return (unsigned short)((u + 0x7FFFu + ((u >> 16) & 1u)) >> 16);
}
__device__ __forceinline__ float bf2f_(unsigned short u) {
    return __uint_as_float(((unsigned)u) << 16);
}

// ---------------- init: hpack = 0, barriers = 0 -----------------------------
__global__ void init_kernel(unsigned short* __restrict__ hpack,
                            unsigned* __restrict__ bar) {
    int i = blockIdx.x * 256 + threadIdx.x;
    if (i < B_ * H_) hpack[i] = 0;
    if (i < 256) bar[i] = 0u;
}

// -------- pack all weights into MFMA B-frag bf16 order ----------------------
// regions (ushort offsets): y:[0,786432) x:[786432,851968) c:[851968,983040)
//                           kv:[983040,1114112)
__global__ void pack_w_kernel(const float* __restrict__ W_gd,
                              const float* __restrict__ W_tau,
                              const float* __restrict__ Wk,
                              const float* __restrict__ Wv,
                              unsigned short* __restrict__ Wpack) {
    int gid = blockIdx.x * 256 + threadIdx.x;
    if (gid >= 1114112) return;
    int j = gid & 7;
    int l = (gid >> 3) & 63;
    int kpart = (l >> 4) * 8 + j;
    int npart = l & 15;
    float v;
    if (gid < 786432) {
        int f = gid >> 9;
        int s = f % 3;
        int rem = f / 3;
        int kb = rem & 15, ct = rem >> 4;
        int k = kb * 32 + kpart;
        int c = ct * 16 + npart;
        if (s == 0)      v = W_gd[(size_t)(D_ + k) * 1024 + c];
        else if (s == 1) v = W_gd[(size_t)(D_ + k) * 1024 + 512 + c];
        else             v = W_tau[(size_t)k * 512 + c];
    } else if (gid < 851968) {
        int r = gid - 786432;
        int f = r >> 9;
        int s = f & 1, kb = (f >> 1) & 1, ct = f >> 2;
        int k = kb * 32 + kpart;
        int c = ct * 16 + npart;
        v = W_gd[(size_t)k * 1024 + s * 512 + c];
    } else if (gid < 983040) {
        int r = gid - 851968;
        int f = r >> 9;
        int s = f & 1, kb = (f >> 1) & 3, ct = f >> 3;
        int k = kb * 32 + kpart;
        int c = ct * 16 + npart;
        v = W_gd[(size_t)(D_ + H_ + k) * 1024 + s * 512 + c];
    } else {
        int r = gid - 983040;
        int f = r >> 9;
        int kb = f & 15, c4 = f >> 4;
        int k = kb * 32 + kpart;
        int n = (c4 & 7) * 16 + npart;
        v = (c4 < 8) ? Wk[(size_t)k * A_ + n] : Wv[(size_t)k * A_ + n];
    }
    Wpack[gid] = f2bf_(v);
}

// ---------------- group barrier: 4 blocks, generation counter ---------------
__device__ __forceinline__ void gsync4(unsigned* barg) {
    __syncthreads();
    if (threadIdx.x == 0) {
        unsigned g = __hip_atomic_load(barg + 1, __ATOMIC_RELAXED,
                                       __HIP_MEMORY_SCOPE_AGENT);
        unsigned old = __hip_atomic_fetch_add(barg, 1u, __ATOMIC_ACQ_REL,
                                              __HIP_MEMORY_SCOPE_AGENT);
        if (old == 3u) {
            __hip_atomic_store(barg, 0u, __ATOMIC_RELAXED,
                               __HIP_MEMORY_SCOPE_AGENT);
            __hip_atomic_fetch_add(barg + 1, 1u, __ATOMIC_ACQ_REL,
                                   __HIP_MEMORY_SCOPE_AGENT);
        } else {
            while (__hip_atomic_load(barg + 1, __ATOMIC_RELAXED,
                                     __HIP_MEMORY_SCOPE_AGENT) == g) {
                __builtin_amdgcn_s_sleep(1);
            }
        }
    }
    __syncthreads();
    __builtin_amdgcn_fence(__ATOMIC_ACQUIRE, "agent");
}

struct P {
    const float *x, *dts, *Wq, *bq, *bk, *bv, *b_gd, *b_tau, *gleak, *cm,
        *W_fc, *b_fc;
    float *h, *ctx, *out, *Kpart, *Vpart;
    unsigned short *Kh, *Vh;  // K: [B][T][A] bf16 ; V: [B][A][T] bf16
    const unsigned short *Wy, *Wx, *Wc, *Wkv;
    unsigned short *hpack, *yapack, *ybpack;
    unsigned* bar;
};

__device__ __forceinline__ void gemm3(const short8 (&wg)[16],
                                      const short8 (&wd)[16],
                                      const short8 (&wt)[16],
                                      const short8* Ap, int m_tile, int lane,
                                      floatx4& ag, floatx4& ad, floatx4& at) {
    #pragma unroll
    for (int kb = 0; kb < 16; ++kb) {
        short8 a = Ap[(m_tile * 16 + kb) * 64 + lane];
        ag = __builtin_amdgcn_mfma_f32_16x16x32_bf16(a, wg[kb], ag, 0, 0, 0);
        ad = __builtin_amdgcn_mfma_f32_16x16x32_bf16(a, wd[kb], ad, 0, 0, 0);
        at = __builtin_amdgcn_mfma_f32_16x16x32_bf16(a, wt[kb], at, 0, 0, 0);
    }
}

__global__ __launch_bounds__(512) void fused_kernel(P p) {
    const int tid = threadIdx.x;
    const int bid = blockIdx.x;
    const int lane = tid & 63;
    const int wave = tid >> 6;            // 0..7
    const int g = bid & 15;               // group: 4 blocks share bid%8 -> XCD
    const int j = bid >> 4;               // block within group 0..3
    const int ct = j * 8 + wave;          // channel strip 0..31
    const int m_tile = g;                 // batch tile (16 rows)
    unsigned* barg = p.bar + g * 16;

    __shared__ float WqL[D_ * 129];
    __shared__ float xs4[4][D_];
    __shared__ float q4[4][A_];
    __shared__ float sc4[4][T_];
    __shared__ float red[4][2];

    // persistent y-part B-fragments (192 VGPRs)
    short8 wg[16], wd[16], wt[16];
    {
        const short8* Wy8 = (const short8*)p.Wy;
        #pragma unroll
        for (int kb = 0; kb < 16; ++kb) {
            wg[kb] = Wy8[((ct * 16 + kb) * 3 + 0) * 64 + lane];
            wd[kb] = Wy8[((ct * 16 + kb) * 3 + 1) * 64 + lane];
            wt[kb] = Wy8[((ct * 16 + kb) * 3 + 2) * 64 + lane];
        }
    }
    const int quad = lane >> 4;
    const int c = ct * 16 + (lane & 15);
    const float btau = p.b_tau[c];
    const float lk = sp_(p.cm[c]) + sp_(p.gleak[c]) + 1e-6f;
    const float bgd_g = p.b_gd[c];
    const float bgd_d = p.b_gd[512 + c];
    const int lane_p = ((c >> 3) & 3) * 16;
    const int pbase = (m_tile * 16 + (c >> 5)) * 512 + (c & 7);

    // attention assignment: sub-row within block
    const int sub = tid >> 7;             // 0..3
    const int tl = tid & 127;
    const int r = g * 16 + j * 4 + sub;   // this block's attention rows
    const int rrow = r & 15;              // row within m_tile

    // Wq -> LDS (stride 129 to break bank alignment)
    for (int i = tid; i < D_ * A_; i += 512) {
        int d = i >> 7, a = i & 127;
        WqL[d * 129 + a] = p.Wq[i];
    }

    floatx4 hreg = {0.f, 0.f, 0.f, 0.f};
    floatx4 rk1, rk2, rk3, baseg, based, ycur, dt4;

    const short8* Wx8 = (const short8*)p.Wx;
    const short8* Wc8 = (const short8*)p.Wc;
    const short8* Wkv8 = (const short8*)p.Wkv;
    const short8* Ahp = (const short8*)p.hpack;
    const short8* Aya = (const short8*)p.yapack;
    const short8* Ayb = (const short8*)p.ybpack;

    __syncthreads();  // WqL ready

    for (int t = 0; t < T_; ++t) {
        // ---------- phase A: attention for 4 rows (128 threads each) --------
        {
            // materialize K/V row t-1 from the 4 per-block partials
            if (t > 0) {
                float ks = p.bk[tl], vs = p.bv[tl];
                #pragma unroll
                for (int jj = 0; jj < 4; ++jj) {
                    ks += p.Kpart[((g * 4 + jj) * 16 + rrow) * 128 + tl];
                    vs += p.Vpart[((g * 4 + jj) * 16 + rrow) * 128 + tl];
                }
                p.Kh[(size_t)(r * T_ + (t - 1)) * A_ + tl] = f2bf_(ks);
                p.Vh[((size_t)r * A_ + tl) * T_ + (t - 1)] = f2bf_(vs);
            }
            if (tl < 16)
                ((float4*)xs4[sub])[tl] =
                    ((const float4*)&p.x[(r * T_ + t) * D_])[tl];
            __syncthreads();  // drains K/V stores + xs4
            float qa = p.bq[tl];
            #pragma unroll 8
            for (int d = 0; d < D_; ++d) qa += xs4[sub][d] * WqL[d * 129 + tl];
            q4[sub][tl] = qa;
            __syncthreads();
            if (t == 0) {
                p.ctx[r * A_ + tl] = 0.f;
            } else {
                const float rscale = 0.08838834764831845f;  // 1/sqrt(128)
                const int grp = tl >> 4, ln = tl & 15;
                float qv[8];
                #pragma unroll
                for (int i = 0; i < 8; ++i) qv[i] = q4[sub][ln * 8 + i];
                for (int s = grp; s < t; s += 8) {
                    ushort8 k8 = *((const ushort8*)(p.Kh +
                                     (size_t)(r * T_ + s) * A_) + ln);
                    float a2 = 0.f;
                    #pragma unroll
                    for (int i = 0; i < 8; ++i) a2 += bf2f_(k8[i]) * qv[i];
                    #pragma unroll
                    for (int off = 8; off > 0; off >>= 1)
                        a2 += __shfl_xor(a2, off, 16);
                    if (ln == 0) sc4[sub][s] = a2 * rscale;
                }
                __syncthreads();
                float mloc = -1e30f;
                for (int s = tl; s < t; s += 128) mloc = fmaxf(mloc, sc4[sub][s]);
                #pragma unroll
                for (int off = 32; off > 0; off >>= 1)
                    mloc = fmaxf(mloc, __shfl_xor(mloc, off, 64));
                if (lane == 0) red[sub][wave & 1] = mloc;
                __syncthreads();
                float m = fmaxf(red[sub][0], red[sub][1]);
                float ssum = 0.f;
                for (int s = tl; s < t; s += 128) {
                    float e = expf(sc4[sub][s] - m);
                    sc4[sub][s] = e;
                    ssum += e;
                }
                #pragma unroll
                for (int off = 32; off > 0; off >>= 1)
                    ssum += __shfl_xor(ssum, off, 64);
                __syncthreads();
                if (lane == 0) red[sub][wave & 1] = ssum;
                __syncthreads();
                float rs = 1.f / (red[sub][0] + red[sub][1]);
                // ctx: V transposed [r][a][T], ushort8 = 8 steps per load
                const unsigned short* Vrow = p.Vh + (size_t)(r * A_ + tl) * T_;
                float ca0 = 0.f, ca1 = 0.f;
                int s0 = 0;
                for (; s0 + 16 <= t; s0 += 16) {
                    ushort8 v0 = *(const ushort8*)(Vrow + s0);
                    ushort8 v1 = *(const ushort8*)(Vrow + s0 + 8);
                    #pragma unroll
                    for (int i = 0; i < 8; ++i) {
                        ca0 += sc4[sub][s0 + i] * bf2f_(v0[i]);
                        ca1 += sc4[sub][s0 + 8 + i] * bf2f_(v1[i]);
                    }
                }
                if (s0 + 8 <= t) {
                    ushort8 v0 = *(const ushort8*)(Vrow + s0);
                    #pragma unroll
                    for (int i = 0; i < 8; ++i)
                        ca0 += sc4[sub][s0 + i] * bf2f_(v0[i]);
                    s0 += 8;
                }
                for (; s0 < t; ++s0) ca0 += sc4[sub][s0] * bf2f_(Vrow[s0]);
                p.ctx[r * A_ + tl] = (ca0 + ca1) * rs;
            }
        }
        gsync4(barg);

        // ---------- phase B: stage1 + base fold (x/ctx MFMA) ----------
        {
            const int mrow = lane & 15;
            const int kq = lane >> 4;
            #pragma unroll
            for (int i = 0; i < 4; ++i)
                dt4[i] = p.dts[(m_tile * 16 + quad * 4 + i) * T_ + t];

            const float4* xrow =
                (const float4*)&p.x[((m_tile * 16 + mrow) * T_ + t) * D_];
            const float4* crow =
                (const float4*)&p.ctx[(m_tile * 16 + mrow) * A_];
            floatx4 bg = {0.f, 0.f, 0.f, 0.f};
            floatx4 bd = {0.f, 0.f, 0.f, 0.f};
            #pragma unroll
            for (int kb = 0; kb < 2; ++kb) {
                float4 u = xrow[kb * 8 + kq * 2], v = xrow[kb * 8 + kq * 2 + 1];
                short8 ax;
                ax[0] = (short)f2bf_(u.x); ax[1] = (short)f2bf_(u.y);
                ax[2] = (short)f2bf_(u.z); ax[3] = (short)f2bf_(u.w);
                ax[4] = (short)f2bf_(v.x); ax[5] = (short)f2bf_(v.y);
                ax[6] = (short)f2bf_(v.z); ax[7] = (short)f2bf_(v.w);
                bg = __builtin_amdgcn_mfma_f32_16x16x32_bf16(
                    ax, Wx8[((ct * 2 + kb) * 2 + 0) * 64 + lane], bg, 0, 0, 0);
                bd = __builtin_amdgcn_mfma_f32_16x16x32_bf16(
                    ax, Wx8[((ct * 2 + kb) * 2 + 1) * 64 + lane], bd, 0, 0, 0);
            }
            #pragma unroll
            for (int kb = 0; kb < 4; ++kb) {
                float4 u = crow[kb * 8 + kq * 2], v = crow[kb * 8 + kq * 2 + 1];
                short8 ac;
                ac[0] = (short)f2bf_(u.x); ac[1] = (short)f2bf_(u.y);
                ac[2] = (short)f2bf_(u.z); ac[3] = (short)f2bf_(u.w);
                ac[4] = (short)f2bf_(v.x); ac[5] = (short)f2bf_(v.y);
                ac[6] = (short)f2bf_(v.z); ac[7] = (short)f2bf_(v.w);
                bg = __builtin_amdgcn_mfma_f32_16x16x32_bf16(
                    ac, Wc8[((ct * 4 + kb) * 2 + 0) * 64 + lane], bg, 0, 0, 0);
                bd = __builtin_amdgcn_mfma_f32_16x16x32_bf16(
                    ac, Wc8[((ct * 4 + kb) * 2 + 1) * 64 + lane], bd, 0, 0, 0);
            }
            floatx4 ag = {0.f, 0.f, 0.f, 0.f};
            floatx4 ad = {0.f, 0.f, 0.f, 0.f};
            floatx4 at = {0.f, 0.f, 0.f, 0.f};
            gemm3(wg, wd, wt, Ahp, m_tile, lane, ag, ad, at);
            #pragma unroll
            for (int i = 0; i < 4; ++i) {
                baseg[i] = bg[i] + bgd_g;
                based[i] = bd[i] + bgd_d;
                float gate = ag[i] + baseg[i];
                float dyn = ad[i] + based[i];
                float tau = sp_(at[i] + btau);
                float ki = (sigm_(gate) * tanhf(dyn) - hreg[i]) / (tau + lk);
                rk1[i] = ki;
                float yn = hreg[i] + dt4[i] * ki * (1.f / 3.f);
                ycur[i] = yn;
                p.yapack[pbase + (lane_p + (quad * 4 + i)) * 8] = f2bf_(yn);
            }
        }
        gsync4(barg);

        // ---------- stage 2 ----------
        {
            floatx4 ag = {0.f, 0.f, 0.f, 0.f};
            floatx4 ad = {0.f, 0.f, 0.f, 0.f};
            floatx4 at = {0.f, 0.f, 0.f, 0.f};
            gemm3(wg, wd, wt, Aya, m_tile, lane, ag, ad, at);
            #pragma unroll
            for (int i = 0; i < 4; ++i) {
                float gate = ag[i] + baseg[i];
                float dyn = ad[i] + based[i];
                float tau = sp_(at[i] + btau);
                float ki = (sigm_(gate) * tanhf(dyn) - ycur[i]) / (tau + lk);
                rk2[i] = ki;
                float yn = hreg[i] + dt4[i] * (ki - rk1[i] * (1.f / 3.f));
                ycur[i] = yn;
                p.ybpack[pbase + (lane_p + (quad * 4 + i)) * 8] = f2bf_(yn);
            }
        }
        gsync4(barg);

        // ---------- stage 3 ----------
        {
            floatx4 ag = {0.f, 0.f, 0.f, 0.f};
            floatx4 ad = {0.f, 0.f, 0.f, 0.f};
            floatx4 at = {0.f, 0.f, 0.f, 0.f};
            gemm3(wg, wd, wt, Ayb, m_tile, lane, ag, ad, at);
            #pragma unroll
            for (int i = 0; i < 4; ++i) {
                float gate = ag[i] + baseg[i];
                float dyn = ad[i] + based[i];
                float tau = sp_(at[i] + btau);
                float ki = (sigm_(gate) * tanhf(dyn) - ycur[i]) / (tau + lk);
                rk3[i] = ki;
                float yn = hreg[i] + dt4[i] * (rk1[i] - rk2[i] + ki);
                ycur[i] = yn;
                p.yapack[pbase + (lane_p + (quad * 4 + i)) * 8] = f2bf_(yn);
            }
        }
        gsync4(barg);

        // ---------- stage 4 + block-local partial K/V projection ----------
        {
            floatx4 ag = {0.f, 0.f, 0.f, 0.f};
            floatx4 ad = {0.f, 0.f, 0.f, 0.f};
            floatx4 at = {0.f, 0.f, 0.f, 0.f};
            gemm3(wg, wd, wt, Aya, m_tile, lane, ag, ad, at);
            #pragma unroll
            for (int i = 0; i < 4; ++i) {
                float gate = ag[i] + baseg[i];
                float dyn = ad[i] + based[i];
                float tau = sp_(at[i] + btau);
                float ki = (sigm_(gate) * tanhf(dyn) - ycur[i]) / (tau + lk);
                hreg[i] = hreg[i] +
                          dt4[i] * (rk1[i] + 3.f * rk2[i] + 3.f * rk3[i] + ki) * 0.125f;
                p.hpack[pbase + (lane_p + (quad * 4 + i)) * 8] = f2bf_(hreg[i]);
            }
            __threadfence_block();
            __syncthreads();  // block's hpack slice (kb in [4j,4j+4)) visible
            // partial K/V over this block's K-range [128j, 128j+128)
            #pragma unroll
            for (int half = 0; half < 2; ++half) {
                const int c4 = wave + half * 8;   // 0..7 = K cols, 8..15 = V
                floatx4 acc = {0.f, 0.f, 0.f, 0.f};
                #pragma unroll
                for (int kk = 0; kk < 4; ++kk) {
                    const int kb = j * 4 + kk;
                    short8 a = Ahp[(m_tile * 16 + kb) * 64 + lane];
                    acc = __builtin_amdgcn_mfma_f32_16x16x32_bf16(
                        a, Wkv8[(c4 * 16 + kb) * 64 + lane], acc, 0, 0, 0);
                }
                const int ac = (c4 & 7) * 16 + (lane & 15);
                float* part = (c4 < 8) ? p.Kpart : p.Vpart;
                #pragma unroll
                for (int i = 0; i < 4; ++i) {
                    const int row = quad * 4 + i;
                    part[((g * 4 + j) * 16 + row) * 128 + ac] = acc[i];
                }
            }
        }
        gsync4(barg);
    }

    // ---------- write final h, then fc ----------
    #pragma unroll
    for (int i = 0; i < 4; ++i)
        p.h[(m_tile * 16 + quad * 4 + i) * H_ + c] = hreg[i];
    gsync4(barg);
    {
        const int o = tl & 31, ks = tl >> 5;  // ks 0..3
        float acc = 0.f;
        #pragma unroll 4
        for (int k = ks * 128; k < ks * 128 + 128; ++k)
            acc += p.h[r * H_ + k] * p.W_fc[k * O_ + o];
        sc4[sub][tl] = acc;
        __syncthreads();
        if (ks == 0)
            p.out[r * O_ + o] = acc + sc4[sub][o + 32] + sc4[sub][o + 64] +
                                sc4[sub][o + 96] + p.b_fc[o];
    }
}

extern "C" void kernel_launch(void* const* d_in, const int* in_sizes, int n_in,
                              void* d_out, int out_size, void* d_ws,
                              size_t ws_size, hipStream_t stream) {
    (void)in_sizes; (void)n_in; (void)out_size; (void)ws_size;
    P p;
    p.x = (const float*)d_in[0];
    p.dts = (const float*)d_in[1];
    p.Wq = (const float*)d_in[2];
    p.bq = (const float*)d_in[3];
    const float* Wk = (const float*)d_in[4];
    p.bk = (const float*)d_in[5];
    const float* Wv = (const float*)d_in[6];
    p.bv = (const float*)d_in[7];
    const float* W_gd = (const float*)d_in[8];
    p.b_gd = (const float*)d_in[9];
    const float* W_tau = (const float*)d_in[10];
    p.b_tau = (const float*)d_in[11];
    p.gleak = (const float*)d_in[12];
    p.cm = (const float*)d_in[13];
    p.W_fc = (const float*)d_in[14];
    p.b_fc = (const float*)d_in[15];
    p.out = (float*)d_out;

    float* ws = (float*)d_ws;
    p.h = ws;                            // B*H fp32
    p.ctx = p.h + B_ * H_;               // B*A fp32
    p.Kpart = p.ctx + B_ * A_;           // 16*4*16*128 fp32
    p.Vpart = p.Kpart + 131072;          // 16*4*16*128 fp32
    unsigned short* Wpack = (unsigned short*)(p.Vpart + 131072);
    p.Wy = Wpack;                        // 786432 ushorts
    p.Wx = Wpack + 786432;               // 65536
    p.Wc = Wpack + 851968;               // 131072
    p.Wkv = Wpack + 983040;              // 131072
    p.hpack = Wpack + 1114112;           // B*H ushorts
    p.yapack = p.hpack + B_ * H_;
    p.ybpack = p.yapack + B_ * H_;
    p.Kh = p.ybpack + B_ * H_;           // B*T*A bf16
    p.Vh = p.Kh + (size_t)B_ * T_ * A_;  // B*A*T bf16 (transposed)
    p.bar = (unsigned*)(p.Vh + (size_t)B_ * T_ * A_);  // 256 uints

    init_kernel<<<512, 256, 0, stream>>>(p.hpack, p.bar);
    pack_w_kernel<<<4352, 256, 0, stream>>>(W_gd, W_tau, Wk, Wv, Wpack);

    // 64 blocks x 512 threads (8 waves). __launch_bounds__(512) with no
    // min-blocks arg -> VGPR cap 256 (8-wave block => >=2 waves/SIMD), so the
    // 192-VGPR weight fragments stay in registers (round-5 spill fixed).
    // All 64 blocks trivially co-resident (1 block/CU) -> barrier safe.
    // Group = 4 blocks sharing bid%8 (XCD-local heuristic).
    fused_kernel<<<dim3(64), dim3(512), 0, stream>>>(p);
}

// Round 7
// 7194.749 us; speedup vs baseline: 1.7232x; 1.6672x over previous
//
#include <hip/hip_runtime.h>
#include <math.h>

#define B_ 256
#define T_ 128
#define D_ 64
#define H_ 512
#define A_ 128
#define O_ 32

typedef __attribute__((ext_vector_type(8))) short short8;
typedef __attribute__((ext_vector_type(8))) unsigned short ushort8;
typedef __attribute__((ext_vector_type(4))) float floatx4;
typedef __attribute__((ext_vector_type(2))) float floatx2;

__device__ __forceinline__ float sp_(float x) {
    return fmaxf(x, 0.f) + log1pf(expf(-fabsf(x)));
}
__device__ __forceinline__ float sigm_(float x) {
    return 1.f / (1.f + expf(-x));
}
__device__ __forceinline__ unsigned short f2bf_(float f) {
    unsigned int u = __float_as_uint(f);
    return (unsigned short)((u + 0x7FFFu + ((u >> 16) & 1u)) >> 16);
}
__device__ __forceinline__ float bf2f_(unsigned short u) {
    return __uint_as_float(((unsigned)u) << 16);
}

// ---- coherent (MALL-level, no-fence) accessors for cross-block data --------
__device__ __forceinline__ void st16_(unsigned short* p, unsigned short v) {
    __hip_atomic_store(p, v, __ATOMIC_RELAXED, __HIP_MEMORY_SCOPE_SYSTEM);
}
__device__ __forceinline__ void stf_(float* p, float v) {
    __hip_atomic_store(p, v, __ATOMIC_RELAXED, __HIP_MEMORY_SCOPE_SYSTEM);
}
__device__ __forceinline__ float ldf_(const float* p) {
    return __hip_atomic_load(p, __ATOMIC_RELAXED, __HIP_MEMORY_SCOPE_SYSTEM);
}
__device__ __forceinline__ unsigned long long ld64_(const unsigned long long* p) {
    return __hip_atomic_load(p, __ATOMIC_RELAXED, __HIP_MEMORY_SCOPE_SYSTEM);
}
__device__ __forceinline__ floatx2 ldf2_(const float* p) {
    unsigned long long u = ld64_((const unsigned long long*)p);
    union { unsigned long long u; floatx2 f; } c;
    c.u = u;
    return c.f;
}

// ---------------- init: hpack = 0, barriers = 0 -----------------------------
__global__ void init_kernel(unsigned short* __restrict__ hpack,
                            unsigned* __restrict__ bar) {
    int i = blockIdx.x * 256 + threadIdx.x;
    if (i < B_ * H_) hpack[i] = 0;
    if (i < 512) bar[i] = 0u;
}

// -------- pack all weights into MFMA B-frag bf16 order ----------------------
__global__ void pack_w_kernel(const float* __restrict__ W_gd,
                              const float* __restrict__ W_tau,
                              const float* __restrict__ Wk,
                              const float* __restrict__ Wv,
                              unsigned short* __restrict__ Wpack) {
    int gid = blockIdx.x * 256 + threadIdx.x;
    if (gid >= 1114112) return;
    int j = gid & 7;
    int l = (gid >> 3) & 63;
    int kpart = (l >> 4) * 8 + j;
    int npart = l & 15;
    float v;
    if (gid < 786432) {
        int f = gid >> 9;
        int s = f % 3;
        int rem = f / 3;
        int kb = rem & 15, ct = rem >> 4;
        int k = kb * 32 + kpart;
        int c = ct * 16 + npart;
        if (s == 0)      v = W_gd[(size_t)(D_ + k) * 1024 + c];
        else if (s == 1) v = W_gd[(size_t)(D_ + k) * 1024 + 512 + c];
        else             v = W_tau[(size_t)k * 512 + c];
    } else if (gid < 851968) {
        int r = gid - 786432;
        int f = r >> 9;
        int s = f & 1, kb = (f >> 1) & 1, ct = f >> 2;
        int k = kb * 32 + kpart;
        int c = ct * 16 + npart;
        v = W_gd[(size_t)k * 1024 + s * 512 + c];
    } else if (gid < 983040) {
        int r = gid - 851968;
        int f = r >> 9;
        int s = f & 1, kb = (f >> 1) & 3, ct = f >> 3;
        int k = kb * 32 + kpart;
        int c = ct * 16 + npart;
        v = W_gd[(size_t)(D_ + H_ + k) * 1024 + s * 512 + c];
    } else {
        int r = gid - 983040;
        int f = r >> 9;
        int kb = f & 15, c4 = f >> 4;
        int k = kb * 32 + kpart;
        int n = (c4 & 7) * 16 + npart;
        v = (c4 < 8) ? Wk[(size_t)k * A_ + n] : Wv[(size_t)k * A_ + n];
    }
    Wpack[gid] = f2bf_(v);
}

// ------ group barrier: 4 blocks, monotonic counter, NO cache fences ---------
__device__ __forceinline__ void gsync4(unsigned* barg) {
    __syncthreads();  // compiler emits vmcnt(0) drain -> our sc stores at MALL
    if (threadIdx.x == 0) {
        unsigned my = __hip_atomic_fetch_add(barg, 1u, __ATOMIC_RELAXED,
                                             __HIP_MEMORY_SCOPE_SYSTEM);
        unsigned target = (my & ~3u) + 4u;
        while (__hip_atomic_load(barg, __ATOMIC_RELAXED,
                                 __HIP_MEMORY_SCOPE_SYSTEM) < target) {
            __builtin_amdgcn_s_sleep(1);
        }
    }
    __syncthreads();
}

struct P {
    const float *x, *dts, *Wq, *bq, *bk, *bv, *b_gd, *b_tau, *gleak, *cm,
        *W_fc, *b_fc;
    float *h, *ctx, *out, *Kpart, *Vpart;
    unsigned short *Kh, *Vh;  // K: [B][T][A] bf16 ; V: [B][A][T] bf16
    const unsigned short *Wy, *Wx, *Wc, *Wkv;
    unsigned short *hpack, *yapack, *ybpack;
    unsigned* bar;
};

__global__ __launch_bounds__(512) void fused_kernel(P p) {
    const int tid = threadIdx.x;
    const int bid = blockIdx.x;
    const int lane = tid & 63;
    const int wave = tid >> 6;            // 0..7
    const int g = bid & 15;               // group of 4 blocks (bid%8 -> XCD)
    const int j = bid >> 4;               // block within group 0..3
    const int ct = j * 8 + wave;          // channel strip 0..31
    const int m_tile = g;                 // batch tile (16 rows)
    unsigned* barg = p.bar + g * 32;

    __shared__ float WqL[D_ * 129];
    __shared__ float xs4[4][D_];
    __shared__ float q4[4][A_];
    __shared__ float sc4[4][T_];
    __shared__ float red[4][2];
    __shared__ unsigned short AsL[16 * 512];  // 16 KB staged A (one m-tile)
    __shared__ unsigned short As2[4 * 512];   // 4 KB h A-frags for kv partial

    const int quad = lane >> 4;
    const int c = ct * 16 + (lane & 15);
    const float btau = p.b_tau[c];
    const float lk = sp_(p.cm[c]) + sp_(p.gleak[c]) + 1e-6f;
    const float bgd_g = p.b_gd[c];
    const float bgd_d = p.b_gd[512 + c];
    const int lane_p = ((c >> 3) & 3) * 16;
    const int pbase = (m_tile * 16 + (c >> 5)) * 512 + (c & 7);

    const int sub = tid >> 7;             // 0..3
    const int tl = tid & 127;
    const int r = g * 16 + j * 4 + sub;   // this block's attention rows
    const int rrow = r & 15;

    for (int i = tid; i < D_ * A_; i += 512) {
        int d = i >> 7, a = i & 127;
        WqL[d * 129 + a] = p.Wq[i];
    }

    floatx4 hreg = {0.f, 0.f, 0.f, 0.f};
    floatx4 rk1, rk2, rk3, baseg, based, ycur, dt4;

    const short8* Wy8 = (const short8*)p.Wy;
    const short8* Wx8 = (const short8*)p.Wx;
    const short8* Wc8 = (const short8*)p.Wc;
    const short8* Wkv8 = (const short8*)p.Wkv;

    __syncthreads();  // WqL ready

    for (int t = 0; t < T_; ++t) {
        // ---------- phase A: K/V merge of t-1 + attention ----------
        {
            if (t > 0) {
                float ks = p.bk[tl], vs = p.bv[tl];
                #pragma unroll
                for (int jj = 0; jj < 4; ++jj) {
                    ks += ldf_(p.Kpart + ((g * 4 + jj) * 16 + rrow) * 128 + tl);
                    vs += ldf_(p.Vpart + ((g * 4 + jj) * 16 + rrow) * 128 + tl);
                }
                p.Kh[(size_t)(r * T_ + (t - 1)) * A_ + tl] = f2bf_(ks);
                p.Vh[((size_t)r * A_ + tl) * T_ + (t - 1)] = f2bf_(vs);
            }
            if (tl < 16)
                ((float4*)xs4[sub])[tl] =
                    ((const float4*)&p.x[(r * T_ + t) * D_])[tl];
            __syncthreads();
            float qa = p.bq[tl];
            #pragma unroll 8
            for (int d = 0; d < D_; ++d) qa += xs4[sub][d] * WqL[d * 129 + tl];
            q4[sub][tl] = qa;
            __syncthreads();
            if (t == 0) {
                stf_(p.ctx + r * A_ + tl, 0.f);
            } else {
                const float rscale = 0.08838834764831845f;  // 1/sqrt(128)
                const int grp = tl >> 4, ln = tl & 15;
                float qv[8];
                #pragma unroll
                for (int i = 0; i < 8; ++i) qv[i] = q4[sub][ln * 8 + i];
                for (int s = grp; s < t; s += 8) {
                    ushort8 k8 = *((const ushort8*)(p.Kh +
                                     (size_t)(r * T_ + s) * A_) + ln);
                    float a2 = 0.f;
                    #pragma unroll
                    for (int i = 0; i < 8; ++i) a2 += bf2f_(k8[i]) * qv[i];
                    #pragma unroll
                    for (int off = 8; off > 0; off >>= 1)
                        a2 += __shfl_xor(a2, off, 16);
                    if (ln == 0) sc4[sub][s] = a2 * rscale;
                }
                __syncthreads();
                float mloc = -1e30f;
                for (int s = tl; s < t; s += 128) mloc = fmaxf(mloc, sc4[sub][s]);
                #pragma unroll
                for (int off = 32; off > 0; off >>= 1)
                    mloc = fmaxf(mloc, __shfl_xor(mloc, off, 64));
                if (lane == 0) red[sub][wave & 1] = mloc;
                __syncthreads();
                float m = fmaxf(red[sub][0], red[sub][1]);
                float ssum = 0.f;
                for (int s = tl; s < t; s += 128) {
                    float e = expf(sc4[sub][s] - m);
                    sc4[sub][s] = e;
                    ssum += e;
                }
                #pragma unroll
                for (int off = 32; off > 0; off >>= 1)
                    ssum += __shfl_xor(ssum, off, 64);
                __syncthreads();
                if (lane == 0) red[sub][wave & 1] = ssum;
                __syncthreads();
                float rs = 1.f / (red[sub][0] + red[sub][1]);
                const unsigned short* Vrow = p.Vh + (size_t)(r * A_ + tl) * T_;
                float ca0 = 0.f, ca1 = 0.f;
                int s0 = 0;
                for (; s0 + 16 <= t; s0 += 16) {
                    ushort8 v0 = *(const ushort8*)(Vrow + s0);
                    ushort8 v1 = *(const ushort8*)(Vrow + s0 + 8);
                    #pragma unroll
                    for (int i = 0; i < 8; ++i) {
                        ca0 += sc4[sub][s0 + i] * bf2f_(v0[i]);
                        ca1 += sc4[sub][s0 + 8 + i] * bf2f_(v1[i]);
                    }
                }
                if (s0 + 8 <= t) {
                    ushort8 v0 = *(const ushort8*)(Vrow + s0);
                    #pragma unroll
                    for (int i = 0; i < 8; ++i)
                        ca0 += sc4[sub][s0 + i] * bf2f_(v0[i]);
                    s0 += 8;
                }
                for (; s0 < t; ++s0) ca0 += sc4[sub][s0] * bf2f_(Vrow[s0]);
                stf_(p.ctx + r * A_ + tl, (ca0 + ca1) * rs);
            }
        }
        gsync4(barg);

        // ---------- phase B: stage1 + base fold ----------
        {
            // stage hpack(m_tile) -> LDS coherently
            {
                const unsigned long long* src =
                    (const unsigned long long*)p.hpack + m_tile * 2048;
                unsigned long long* dst = (unsigned long long*)AsL;
                #pragma unroll
                for (int i = 0; i < 4; ++i)
                    dst[tid + i * 512] = ld64_(src + tid + i * 512);
            }
            __syncthreads();

            const int mrow = lane & 15;
            const int kq = lane >> 4;
            #pragma unroll
            for (int i = 0; i < 4; ++i)
                dt4[i] = p.dts[(m_tile * 16 + quad * 4 + i) * T_ + t];

            floatx4 bg = {0.f, 0.f, 0.f, 0.f};
            floatx4 bd = {0.f, 0.f, 0.f, 0.f};
            const float4* xrow =
                (const float4*)&p.x[((m_tile * 16 + mrow) * T_ + t) * D_];
            #pragma unroll
            for (int kb = 0; kb < 2; ++kb) {
                float4 u = xrow[kb * 8 + kq * 2], v = xrow[kb * 8 + kq * 2 + 1];
                short8 ax;
                ax[0] = (short)f2bf_(u.x); ax[1] = (short)f2bf_(u.y);
                ax[2] = (short)f2bf_(u.z); ax[3] = (short)f2bf_(u.w);
                ax[4] = (short)f2bf_(v.x); ax[5] = (short)f2bf_(v.y);
                ax[6] = (short)f2bf_(v.z); ax[7] = (short)f2bf_(v.w);
                bg = __builtin_amdgcn_mfma_f32_16x16x32_bf16(
                    ax, Wx8[((ct * 2 + kb) * 2 + 0) * 64 + lane], bg, 0, 0, 0);
                bd = __builtin_amdgcn_mfma_f32_16x16x32_bf16(
                    ax, Wx8[((ct * 2 + kb) * 2 + 1) * 64 + lane], bd, 0, 0, 0);
            }
            const float* crow = &p.ctx[(m_tile * 16 + mrow) * A_];
            #pragma unroll
            for (int kb = 0; kb < 4; ++kb) {
                short8 ac;
                #pragma unroll
                for (int q2 = 0; q2 < 4; ++q2) {
                    floatx2 f = ldf2_(crow + kb * 32 + kq * 8 + q2 * 2);
                    ac[q2 * 2] = (short)f2bf_(f.x);
                    ac[q2 * 2 + 1] = (short)f2bf_(f.y);
                }
                bg = __builtin_amdgcn_mfma_f32_16x16x32_bf16(
                    ac, Wc8[((ct * 4 + kb) * 2 + 0) * 64 + lane], bg, 0, 0, 0);
                bd = __builtin_amdgcn_mfma_f32_16x16x32_bf16(
                    ac, Wc8[((ct * 4 + kb) * 2 + 1) * 64 + lane], bd, 0, 0, 0);
            }
            floatx4 ag = {0.f, 0.f, 0.f, 0.f};
            floatx4 ad = {0.f, 0.f, 0.f, 0.f};
            floatx4 at = {0.f, 0.f, 0.f, 0.f};
            #pragma unroll
            for (int kb = 0; kb < 16; ++kb) {
                short8 a = *(const short8*)(AsL + (kb * 64 + lane) * 8);
                ag = __builtin_amdgcn_mfma_f32_16x16x32_bf16(
                    a, Wy8[((ct * 16 + kb) * 3 + 0) * 64 + lane], ag, 0, 0, 0);
                ad = __builtin_amdgcn_mfma_f32_16x16x32_bf16(
                    a, Wy8[((ct * 16 + kb) * 3 + 1) * 64 + lane], ad, 0, 0, 0);
                at = __builtin_amdgcn_mfma_f32_16x16x32_bf16(
                    a, Wy8[((ct * 16 + kb) * 3 + 2) * 64 + lane], at, 0, 0, 0);
            }
            #pragma unroll
            for (int i = 0; i < 4; ++i) {
                baseg[i] = bg[i] + bgd_g;
                based[i] = bd[i] + bgd_d;
                float gate = ag[i] + baseg[i];
                float dyn = ad[i] + based[i];
                float tau = sp_(at[i] + btau);
                float ki = (sigm_(gate) * tanhf(dyn) - hreg[i]) / (tau + lk);
                rk1[i] = ki;
                float yn = hreg[i] + dt4[i] * ki * (1.f / 3.f);
                ycur[i] = yn;
                st16_(p.yapack + pbase + (lane_p + (quad * 4 + i)) * 8, f2bf_(yn));
            }
        }
        gsync4(barg);

        // ---------- stages 2..4 ----------
        #pragma unroll 1
        for (int stage = 2; stage <= 4; ++stage) {
            const unsigned short* ysrc =
                (stage == 2) ? p.yapack : (stage == 3) ? p.ybpack : p.yapack;
            unsigned short* ydst =
                (stage == 2) ? p.ybpack : (stage == 3) ? p.yapack : p.hpack;
            {
                const unsigned long long* src =
                    (const unsigned long long*)ysrc + m_tile * 2048;
                unsigned long long* dst = (unsigned long long*)AsL;
                #pragma unroll
                for (int i = 0; i < 4; ++i)
                    dst[tid + i * 512] = ld64_(src + tid + i * 512);
            }
            __syncthreads();
            floatx4 ag = {0.f, 0.f, 0.f, 0.f};
            floatx4 ad = {0.f, 0.f, 0.f, 0.f};
            floatx4 at = {0.f, 0.f, 0.f, 0.f};
            #pragma unroll
            for (int kb = 0; kb < 16; ++kb) {
                short8 a = *(const short8*)(AsL + (kb * 64 + lane) * 8);
                ag = __builtin_amdgcn_mfma_f32_16x16x32_bf16(
                    a, Wy8[((ct * 16 + kb) * 3 + 0) * 64 + lane], ag, 0, 0, 0);
                ad = __builtin_amdgcn_mfma_f32_16x16x32_bf16(
                    a, Wy8[((ct * 16 + kb) * 3 + 1) * 64 + lane], ad, 0, 0, 0);
                at = __builtin_amdgcn_mfma_f32_16x16x32_bf16(
                    a, Wy8[((ct * 16 + kb) * 3 + 2) * 64 + lane], at, 0, 0, 0);
            }
            #pragma unroll
            for (int i = 0; i < 4; ++i) {
                float gate = ag[i] + baseg[i];
                float dyn = ad[i] + based[i];
                float tau = sp_(at[i] + btau);
                float ki = (sigm_(gate) * tanhf(dyn) - ycur[i]) / (tau + lk);
                float yn;
                if (stage == 2) {
                    rk2[i] = ki;
                    yn = hreg[i] + dt4[i] * (ki - rk1[i] * (1.f / 3.f));
                } else if (stage == 3) {
                    rk3[i] = ki;
                    yn = hreg[i] + dt4[i] * (rk1[i] - rk2[i] + ki);
                } else {
                    yn = hreg[i] +
                         dt4[i] * (rk1[i] + 3.f * rk2[i] + 3.f * rk3[i] + ki) * 0.125f;
                    hreg[i] = yn;
                }
                ycur[i] = yn;
                st16_(ydst + pbase + (lane_p + (quad * 4 + i)) * 8, f2bf_(yn));
            }
            if (stage == 4) {
                // block-local h A-frags for kv partial
                const int lbase = (wave >> 1) * 512 + (c & 7);
                #pragma unroll
                for (int i = 0; i < 4; ++i)
                    As2[lbase + (lane_p + (quad * 4 + i)) * 8] = f2bf_(hreg[i]);
                __syncthreads();
                #pragma unroll
                for (int half = 0; half < 2; ++half) {
                    const int c4 = wave + half * 8;
                    floatx4 acc = {0.f, 0.f, 0.f, 0.f};
                    #pragma unroll
                    for (int kk = 0; kk < 4; ++kk) {
                        short8 a = *(const short8*)(As2 + (kk * 64 + lane) * 8);
                        acc = __builtin_amdgcn_mfma_f32_16x16x32_bf16(
                            a, Wkv8[(c4 * 16 + (j * 4 + kk)) * 64 + lane], acc,
                            0, 0, 0);
                    }
                    const int ac = (c4 & 7) * 16 + (lane & 15);
                    float* part = (c4 < 8) ? p.Kpart : p.Vpart;
                    #pragma unroll
                    for (int i = 0; i < 4; ++i)
                        stf_(part + ((g * 4 + j) * 16 + quad * 4 + i) * 128 + ac,
                             acc[i]);
                }
            }
            gsync4(barg);
        }
    }

    // ---------- write final h, then fc ----------
    #pragma unroll
    for (int i = 0; i < 4; ++i)
        stf_(p.h + (m_tile * 16 + quad * 4 + i) * H_ + c, hreg[i]);
    gsync4(barg);
    {
        const int o = tl & 31, ks = tl >> 5;  // ks 0..3
        float acc = 0.f;
        const float* hrow = p.h + r * H_ + ks * 128;
        const float* wcol = p.W_fc + ks * 128 * O_ + o;
        #pragma unroll 8
        for (int k = 0; k < 128; k += 2) {
            floatx2 hv = ldf2_(hrow + k);
            acc += hv.x * wcol[k * O_] + hv.y * wcol[(k + 1) * O_];
        }
        sc4[sub][tl] = acc;
        __syncthreads();
        if (ks == 0)
            p.out[r * O_ + o] = acc + sc4[sub][o + 32] + sc4[sub][o + 64] +
                                sc4[sub][o + 96] + p.b_fc[o];
    }
}

extern "C" void kernel_launch(void* const* d_in, const int* in_sizes, int n_in,
                              void* d_out, int out_size, void* d_ws,
                              size_t ws_size, hipStream_t stream) {
    (void)in_sizes; (void)n_in; (void)out_size; (void)ws_size;
    P p;
    p.x = (const float*)d_in[0];
    p.dts = (const float*)d_in[1];
    p.Wq = (const float*)d_in[2];
    p.bq = (const float*)d_in[3];
    const float* Wk = (const float*)d_in[4];
    p.bk = (const float*)d_in[5];
    const float* Wv = (const float*)d_in[6];
    p.bv = (const float*)d_in[7];
    const float* W_gd = (const float*)d_in[8];
    p.b_gd = (const float*)d_in[9];
    const float* W_tau = (const float*)d_in[10];
    p.b_tau = (const float*)d_in[11];
    p.gleak = (const float*)d_in[12];
    p.cm = (const float*)d_in[13];
    p.W_fc = (const float*)d_in[14];
    p.b_fc = (const float*)d_in[15];
    p.out = (float*)d_out;

    float* ws = (float*)d_ws;
    p.h = ws;                            // B*H fp32
    p.ctx = p.h + B_ * H_;               // B*A fp32
    p.Kpart = p.ctx + B_ * A_;           // 64*16*128 fp32
    p.Vpart = p.Kpart + 131072;          // 64*16*128 fp32
    unsigned short* Wpack = (unsigned short*)(p.Vpart + 131072);
    p.Wy = Wpack;                        // 786432 ushorts
    p.Wx = Wpack + 786432;               // 65536
    p.Wc = Wpack + 851968;               // 131072
    p.Wkv = Wpack + 983040;              // 131072
    p.hpack = Wpack + 1114112;           // B*H ushorts
    p.yapack = p.hpack + B_ * H_;
    p.ybpack = p.yapack + B_ * H_;
    p.Kh = p.ybpack + B_ * H_;           // B*T*A bf16
    p.Vh = p.Kh + (size_t)B_ * T_ * A_;  // B*A*T bf16 (transposed)
    p.bar = (unsigned*)(p.Vh + (size_t)B_ * T_ * A_);  // 512 uints

    init_kernel<<<512, 256, 0, stream>>>(p.hpack, p.bar);
    pack_w_kernel<<<4352, 256, 0, stream>>>(W_gd, W_tau, Wk, Wv, Wpack);

    // 64 blocks x 512 threads (8 waves). No persistent weight registers ->
    // low VGPR (no spill regardless of compiler's occupancy cap). Weights
    // stream from L2, which stays warm because barriers no longer flush it:
    // all cross-block data moves via system-scope (MALL-coherent) accesses
    // and the barrier is a relaxed monotonic counter with zero fences.
    fused_kernel<<<dim3(64), dim3(512), 0, stream>>>(p);
}

// Round 8
// 4781.606 us; speedup vs baseline: 2.5929x; 1.5047x over previous
//
#include <hip/hip_runtime.h>
#include <math.h>

#define B_ 256
#define T_ 128
#define D_ 64
#define H_ 512
#define A_ 128
#define O_ 32

typedef __attribute__((ext_vector_type(8))) short short8;
typedef __attribute__((ext_vector_type(8))) unsigned short ushort8;
typedef __attribute__((ext_vector_type(4))) float floatx4;
typedef __attribute__((ext_vector_type(2))) float floatx2;

__device__ __forceinline__ float sp_(float x) {
    return fmaxf(x, 0.f) + log1pf(expf(-fabsf(x)));
}
__device__ __forceinline__ float sigm_(float x) {
    return 1.f / (1.f + expf(-x));
}
__device__ __forceinline__ unsigned short f2bf_(float f) {
    unsigned int u = __float_as_uint(f);
    return (unsigned short)((u + 0x7FFFu + ((u >> 16) & 1u)) >> 16);
}
__device__ __forceinline__ float bf2f_(unsigned short u) {
    return __uint_as_float(((unsigned)u) << 16);
}

// ---- coherent (MALL-level, no-fence) accessors for cross-block data --------
__device__ __forceinline__ void st16_(unsigned short* p, unsigned short v) {
    __hip_atomic_store(p, v, __ATOMIC_RELAXED, __HIP_MEMORY_SCOPE_SYSTEM);
}
__device__ __forceinline__ void stf_(float* p, float v) {
    __hip_atomic_store(p, v, __ATOMIC_RELAXED, __HIP_MEMORY_SCOPE_SYSTEM);
}
__device__ __forceinline__ float ldf_(const float* p) {
    return __hip_atomic_load(p, __ATOMIC_RELAXED, __HIP_MEMORY_SCOPE_SYSTEM);
}
__device__ __forceinline__ unsigned long long ld64_(const unsigned long long* p) {
    return __hip_atomic_load(p, __ATOMIC_RELAXED, __HIP_MEMORY_SCOPE_SYSTEM);
}
__device__ __forceinline__ floatx2 ldf2_(const float* p) {
    unsigned long long u = ld64_((const unsigned long long*)p);
    union { unsigned long long u; floatx2 f; } c;
    c.u = u;
    return c.f;
}

// ---------------- init: hpack = 0, barriers = 0 -----------------------------
__global__ void init_kernel(unsigned short* __restrict__ hpack,
                            unsigned* __restrict__ bar) {
    int i = blockIdx.x * 256 + threadIdx.x;
    if (i < B_ * H_) hpack[i] = 0;
    if (i < 512) bar[i] = 0u;
}

// -------- pack all weights into MFMA B-frag bf16 order ----------------------
__global__ void pack_w_kernel(const float* __restrict__ W_gd,
                              const float* __restrict__ W_tau,
                              const float* __restrict__ Wk,
                              const float* __restrict__ Wv,
                              unsigned short* __restrict__ Wpack) {
    int gid = blockIdx.x * 256 + threadIdx.x;
    if (gid >= 1114112) return;
    int j = gid & 7;
    int l = (gid >> 3) & 63;
    int kpart = (l >> 4) * 8 + j;
    int npart = l & 15;
    float v;
    if (gid < 786432) {
        int f = gid >> 9;
        int s = f % 3;
        int rem = f / 3;
        int kb = rem & 15, ct = rem >> 4;
        int k = kb * 32 + kpart;
        int c = ct * 16 + npart;
        if (s == 0)      v = W_gd[(size_t)(D_ + k) * 1024 + c];
        else if (s == 1) v = W_gd[(size_t)(D_ + k) * 1024 + 512 + c];
        else             v = W_tau[(size_t)k * 512 + c];
    } else if (gid < 851968) {
        int r = gid - 786432;
        int f = r >> 9;
        int s = f & 1, kb = (f >> 1) & 1, ct = f >> 2;
        int k = kb * 32 + kpart;
        int c = ct * 16 + npart;
        v = W_gd[(size_t)k * 1024 + s * 512 + c];
    } else if (gid < 983040) {
        int r = gid - 851968;
        int f = r >> 9;
        int s = f & 1, kb = (f >> 1) & 3, ct = f >> 3;
        int k = kb * 32 + kpart;
        int c = ct * 16 + npart;
        v = W_gd[(size_t)(D_ + H_ + k) * 1024 + s * 512 + c];
    } else {
        int r = gid - 983040;
        int f = r >> 9;
        int kb = f & 15, c4 = f >> 4;
        int k = kb * 32 + kpart;
        int n = (c4 & 7) * 16 + npart;
        v = (c4 < 8) ? Wk[(size_t)k * A_ + n] : Wv[(size_t)k * A_ + n];
    }
    Wpack[gid] = f2bf_(v);
}

// ------ group barrier: 8 blocks, monotonic counter, NO cache fences ---------
__device__ __forceinline__ void gsync8(unsigned* barg) {
    __syncthreads();  // vmcnt(0) drain -> our system-scope stores are visible
    if (threadIdx.x == 0) {
        unsigned my = __hip_atomic_fetch_add(barg, 1u, __ATOMIC_RELAXED,
                                             __HIP_MEMORY_SCOPE_SYSTEM);
        unsigned target = (my & ~7u) + 8u;
        while (__hip_atomic_load(barg, __ATOMIC_RELAXED,
                                 __HIP_MEMORY_SCOPE_SYSTEM) < target) {
            __builtin_amdgcn_s_sleep(1);
        }
    }
    __syncthreads();
}

struct P {
    const float *x, *dts, *Wq, *bq, *bk, *bv, *b_gd, *b_tau, *gleak, *cm,
        *W_fc, *b_fc;
    float *h, *ctx, *out, *Kpart, *Vpart;
    unsigned short *Kh, *Vh;  // K: [B][T][A] bf16 ; V: [B][A][T] bf16
    const unsigned short *Wy, *Wx, *Wc, *Wkv;
    unsigned short *hpack, *yapack, *ybpack;
    unsigned* bar;
};

__global__ __launch_bounds__(256, 1) void fused_kernel(P p) {
    const int tid = threadIdx.x;
    const int bid = blockIdx.x;
    const int lane = tid & 63;
    const int wave = tid >> 6;            // 0..3
    const int g = bid & 15;               // group of 8 blocks (bid%8 -> XCD)
    const int j = bid >> 4;               // block within group 0..7
    const int ct = j * 4 + wave;          // channel strip 0..31
    const int m_tile = g;                 // batch tile (16 rows)
    unsigned* barg = p.bar + g * 32;

    __shared__ float WqL[D_ * 129];
    __shared__ float xs4[2][D_];
    __shared__ float q4[2][A_];
    __shared__ float sc4[2][T_];
    __shared__ float red[2][2];
    __shared__ unsigned short AsL[16 * 512];  // 16 KB staged A (one m-tile)
    __shared__ unsigned short As2[2 * 512];   // 2 KB h A-frags for kv partial

    const int quad = lane >> 4;
    const int c = ct * 16 + (lane & 15);
    const float btau = p.b_tau[c];
    const float lk = sp_(p.cm[c]) + sp_(p.gleak[c]) + 1e-6f;
    const float bgd_g = p.b_gd[c];
    const float bgd_d = p.b_gd[512 + c];
    const int lane_p = ((c >> 3) & 3) * 16;
    const int pbase = (m_tile * 16 + (c >> 5)) * 512 + (c & 7);

    const int sub = tid >> 7;             // 0..1
    const int tl = tid & 127;
    const int r = g * 16 + j * 2 + sub;   // this block's 2 attention rows
    const int rrow = r & 15;

    // ---- persistent register weights: 48 + 4 + 8 = 60 frags (240 VGPRs) ----
    short8 wg[16], wd[16], wt[16];
    short8 wxg[2], wxd[2], wcg[4], wcd[4];
    {
        const short8* Wy8 = (const short8*)p.Wy;
        #pragma unroll
        for (int kb = 0; kb < 16; ++kb) {
            wg[kb] = Wy8[((ct * 16 + kb) * 3 + 0) * 64 + lane];
            wd[kb] = Wy8[((ct * 16 + kb) * 3 + 1) * 64 + lane];
            wt[kb] = Wy8[((ct * 16 + kb) * 3 + 2) * 64 + lane];
        }
        const short8* Wx8 = (const short8*)p.Wx;
        const short8* Wc8 = (const short8*)p.Wc;
        #pragma unroll
        for (int kb = 0; kb < 2; ++kb) {
            wxg[kb] = Wx8[((ct * 2 + kb) * 2 + 0) * 64 + lane];
            wxd[kb] = Wx8[((ct * 2 + kb) * 2 + 1) * 64 + lane];
        }
        #pragma unroll
        for (int kb = 0; kb < 4; ++kb) {
            wcg[kb] = Wc8[((ct * 4 + kb) * 2 + 0) * 64 + lane];
            wcd[kb] = Wc8[((ct * 4 + kb) * 2 + 1) * 64 + lane];
        }
    }

    for (int i = tid; i < D_ * A_; i += 256) {
        int d = i >> 7, a = i & 127;
        WqL[d * 129 + a] = p.Wq[i];
    }

    floatx4 hreg = {0.f, 0.f, 0.f, 0.f};
    floatx4 rk1, rk2, rk3, baseg, based, ycur, dt4;

    const short8* Wkv8 = (const short8*)p.Wkv;

    __syncthreads();  // WqL ready

    for (int t = 0; t < T_; ++t) {
        // ---------- phase A: K/V merge of t-1 + attention (2 rows) ----------
        {
            if (t > 0) {
                float ks = p.bk[tl], vs = p.bv[tl];
                #pragma unroll
                for (int jj = 0; jj < 8; ++jj) {
                    ks += ldf_(p.Kpart + ((g * 8 + jj) * 16 + rrow) * 128 + tl);
                    vs += ldf_(p.Vpart + ((g * 8 + jj) * 16 + rrow) * 128 + tl);
                }
                p.Kh[(size_t)(r * T_ + (t - 1)) * A_ + tl] = f2bf_(ks);
                p.Vh[((size_t)r * A_ + tl) * T_ + (t - 1)] = f2bf_(vs);
            }
            if (tl < 16)
                ((float4*)xs4[sub])[tl] =
                    ((const float4*)&p.x[(r * T_ + t) * D_])[tl];
            __syncthreads();
            float qa = p.bq[tl];
            #pragma unroll 8
            for (int d = 0; d < D_; ++d) qa += xs4[sub][d] * WqL[d * 129 + tl];
            q4[sub][tl] = qa;
            __syncthreads();
            if (t == 0) {
                stf_(p.ctx + r * A_ + tl, 0.f);
            } else {
                const float rscale = 0.08838834764831845f;  // 1/sqrt(128)
                const int grp = tl >> 4, ln = tl & 15;
                float qv[8];
                #pragma unroll
                for (int i = 0; i < 8; ++i) qv[i] = q4[sub][ln * 8 + i];
                for (int s = grp; s < t; s += 8) {
                    ushort8 k8 = *((const ushort8*)(p.Kh +
                                     (size_t)(r * T_ + s) * A_) + ln);
                    float a2 = 0.f;
                    #pragma unroll
                    for (int i = 0; i < 8; ++i) a2 += bf2f_(k8[i]) * qv[i];
                    #pragma unroll
                    for (int off = 8; off > 0; off >>= 1)
                        a2 += __shfl_xor(a2, off, 16);
                    if (ln == 0) sc4[sub][s] = a2 * rscale;
                }
                __syncthreads();
                float mloc = -1e30f;
                for (int s = tl; s < t; s += 128) mloc = fmaxf(mloc, sc4[sub][s]);
                #pragma unroll
                for (int off = 32; off > 0; off >>= 1)
                    mloc = fmaxf(mloc, __shfl_xor(mloc, off, 64));
                if (lane == 0) red[sub][wave & 1] = mloc;
                __syncthreads();
                float m = fmaxf(red[sub][0], red[sub][1]);
                float ssum = 0.f;
                for (int s = tl; s < t; s += 128) {
                    float e = expf(sc4[sub][s] - m);
                    sc4[sub][s] = e;
                    ssum += e;
                }
                #pragma unroll
                for (int off = 32; off > 0; off >>= 1)
                    ssum += __shfl_xor(ssum, off, 64);
                __syncthreads();
                if (lane == 0) red[sub][wave & 1] = ssum;
                __syncthreads();
                float rs = 1.f / (red[sub][0] + red[sub][1]);
                const unsigned short* Vrow = p.Vh + (size_t)(r * A_ + tl) * T_;
                float ca0 = 0.f, ca1 = 0.f;
                int s0 = 0;
                for (; s0 + 16 <= t; s0 += 16) {
                    ushort8 v0 = *(const ushort8*)(Vrow + s0);
                    ushort8 v1 = *(const ushort8*)(Vrow + s0 + 8);
                    #pragma unroll
                    for (int i = 0; i < 8; ++i) {
                        ca0 += sc4[sub][s0 + i] * bf2f_(v0[i]);
                        ca1 += sc4[sub][s0 + 8 + i] * bf2f_(v1[i]);
                    }
                }
                if (s0 + 8 <= t) {
                    ushort8 v0 = *(const ushort8*)(Vrow + s0);
                    #pragma unroll
                    for (int i = 0; i < 8; ++i)
                        ca0 += sc4[sub][s0 + i] * bf2f_(v0[i]);
                    s0 += 8;
                }
                for (; s0 < t; ++s0) ca0 += sc4[sub][s0] * bf2f_(Vrow[s0]);
                stf_(p.ctx + r * A_ + tl, (ca0 + ca1) * rs);
            }
        }
        gsync8(barg);

        // ---------- phase B: stage1 + base fold (register weights) ----------
        {
            {
                const unsigned long long* src =
                    (const unsigned long long*)p.hpack + m_tile * 2048;
                unsigned long long* dst = (unsigned long long*)AsL;
                #pragma unroll
                for (int i = 0; i < 8; ++i)
                    dst[tid + i * 256] = ld64_(src + tid + i * 256);
            }
            __syncthreads();

            const int mrow = lane & 15;
            const int kq = lane >> 4;
            #pragma unroll
            for (int i = 0; i < 4; ++i)
                dt4[i] = p.dts[(m_tile * 16 + quad * 4 + i) * T_ + t];

            floatx4 bg = {0.f, 0.f, 0.f, 0.f};
            floatx4 bd = {0.f, 0.f, 0.f, 0.f};
            const float4* xrow =
                (const float4*)&p.x[((m_tile * 16 + mrow) * T_ + t) * D_];
            #pragma unroll
            for (int kb = 0; kb < 2; ++kb) {
                float4 u = xrow[kb * 8 + kq * 2], v = xrow[kb * 8 + kq * 2 + 1];
                short8 ax;
                ax[0] = (short)f2bf_(u.x); ax[1] = (short)f2bf_(u.y);
                ax[2] = (short)f2bf_(u.z); ax[3] = (short)f2bf_(u.w);
                ax[4] = (short)f2bf_(v.x); ax[5] = (short)f2bf_(v.y);
                ax[6] = (short)f2bf_(v.z); ax[7] = (short)f2bf_(v.w);
                bg = __builtin_amdgcn_mfma_f32_16x16x32_bf16(ax, wxg[kb], bg, 0, 0, 0);
                bd = __builtin_amdgcn_mfma_f32_16x16x32_bf16(ax, wxd[kb], bd, 0, 0, 0);
            }
            const float* crow = &p.ctx[(m_tile * 16 + mrow) * A_];
            #pragma unroll
            for (int kb = 0; kb < 4; ++kb) {
                short8 ac;
                #pragma unroll
                for (int q2 = 0; q2 < 4; ++q2) {
                    floatx2 f = ldf2_(crow + kb * 32 + kq * 8 + q2 * 2);
                    ac[q2 * 2] = (short)f2bf_(f.x);
                    ac[q2 * 2 + 1] = (short)f2bf_(f.y);
                }
                bg = __builtin_amdgcn_mfma_f32_16x16x32_bf16(ac, wcg[kb], bg, 0, 0, 0);
                bd = __builtin_amdgcn_mfma_f32_16x16x32_bf16(ac, wcd[kb], bd, 0, 0, 0);
            }
            floatx4 ag = {0.f, 0.f, 0.f, 0.f};
            floatx4 ad = {0.f, 0.f, 0.f, 0.f};
            floatx4 at = {0.f, 0.f, 0.f, 0.f};
            #pragma unroll
            for (int kb = 0; kb < 16; ++kb) {
                short8 a = *(const short8*)(AsL + (kb * 64 + lane) * 8);
                ag = __builtin_amdgcn_mfma_f32_16x16x32_bf16(a, wg[kb], ag, 0, 0, 0);
                ad = __builtin_amdgcn_mfma_f32_16x16x32_bf16(a, wd[kb], ad, 0, 0, 0);
                at = __builtin_amdgcn_mfma_f32_16x16x32_bf16(a, wt[kb], at, 0, 0, 0);
            }
            #pragma unroll
            for (int i = 0; i < 4; ++i) {
                baseg[i] = bg[i] + bgd_g;
                based[i] = bd[i] + bgd_d;
                float gate = ag[i] + baseg[i];
                float dyn = ad[i] + based[i];
                float tau = sp_(at[i] + btau);
                float ki = (sigm_(gate) * tanhf(dyn) - hreg[i]) / (tau + lk);
                rk1[i] = ki;
                float yn = hreg[i] + dt4[i] * ki * (1.f / 3.f);
                ycur[i] = yn;
                st16_(p.yapack + pbase + (lane_p + (quad * 4 + i)) * 8, f2bf_(yn));
            }
        }
        gsync8(barg);

        // ---------- stages 2..4 ----------
        #pragma unroll 1
        for (int stage = 2; stage <= 4; ++stage) {
            const unsigned short* ysrc =
                (stage == 2) ? p.yapack : (stage == 3) ? p.ybpack : p.yapack;
            unsigned short* ydst =
                (stage == 2) ? p.ybpack : (stage == 3) ? p.yapack : p.hpack;
            {
                const unsigned long long* src =
                    (const unsigned long long*)ysrc + m_tile * 2048;
                unsigned long long* dst = (unsigned long long*)AsL;
                #pragma unroll
                for (int i = 0; i < 8; ++i)
                    dst[tid + i * 256] = ld64_(src + tid + i * 256);
            }
            __syncthreads();
            floatx4 ag = {0.f, 0.f, 0.f, 0.f};
            floatx4 ad = {0.f, 0.f, 0.f, 0.f};
            floatx4 at = {0.f, 0.f, 0.f, 0.f};
            #pragma unroll
            for (int kb = 0; kb < 16; ++kb) {
                short8 a = *(const short8*)(AsL + (kb * 64 + lane) * 8);
                ag = __builtin_amdgcn_mfma_f32_16x16x32_bf16(a, wg[kb], ag, 0, 0, 0);
                ad = __builtin_amdgcn_mfma_f32_16x16x32_bf16(a, wd[kb], ad, 0, 0, 0);
                at = __builtin_amdgcn_mfma_f32_16x16x32_bf16(a, wt[kb], at, 0, 0, 0);
            }
            #pragma unroll
            for (int i = 0; i < 4; ++i) {
                float gate = ag[i] + baseg[i];
                float dyn = ad[i] + based[i];
                float tau = sp_(at[i] + btau);
                float ki = (sigm_(gate) * tanhf(dyn) - ycur[i]) / (tau + lk);
                float yn;
                if (stage == 2) {
                    rk2[i] = ki;
                    yn = hreg[i] + dt4[i] * (ki - rk1[i] * (1.f / 3.f));
                } else if (stage == 3) {
                    rk3[i] = ki;
                    yn = hreg[i] + dt4[i] * (rk1[i] - rk2[i] + ki);
                } else {
                    yn = hreg[i] +
                         dt4[i] * (rk1[i] + 3.f * rk2[i] + 3.f * rk3[i] + ki) * 0.125f;
                    hreg[i] = yn;
                }
                ycur[i] = yn;
                st16_(ydst + pbase + (lane_p + (quad * 4 + i)) * 8, f2bf_(yn));
            }
            if (stage == 4) {
                // block-local h A-frags (this block's 2 kb strips)
                const int lbase = (wave >> 1) * 512 + (c & 7);
                #pragma unroll
                for (int i = 0; i < 4; ++i)
                    As2[lbase + (lane_p + (quad * 4 + i)) * 8] = f2bf_(hreg[i]);
                __syncthreads();
                // partial K/V over this block's K-range [128j, 128j+128)
                #pragma unroll
                for (int h4 = 0; h4 < 4; ++h4) {
                    const int c4 = wave + h4 * 4;  // 0..15 (0..7=K, 8..15=V)
                    floatx4 acc = {0.f, 0.f, 0.f, 0.f};
                    #pragma unroll
                    for (int kk = 0; kk < 2; ++kk) {
                        short8 a = *(const short8*)(As2 + (kk * 64 + lane) * 8);
                        acc = __builtin_amdgcn_mfma_f32_16x16x32_bf16(
                            a, Wkv8[(c4 * 16 + (j * 2 + kk)) * 64 + lane], acc,
                            0, 0, 0);
                    }
                    const int ac = (c4 & 7) * 16 + (lane & 15);
                    float* part = (c4 < 8) ? p.Kpart : p.Vpart;
                    #pragma unroll
                    for (int i = 0; i < 4; ++i)
                        stf_(part + ((g * 8 + j) * 16 + quad * 4 + i) * 128 + ac,
                             acc[i]);
                }
            }
            gsync8(barg);
        }
    }

    // ---------- write final h, then fc ----------
    #pragma unroll
    for (int i = 0; i < 4; ++i)
        stf_(p.h + (m_tile * 16 + quad * 4 + i) * H_ + c, hreg[i]);
    gsync8(barg);
    {
        const int o = tl & 31, ks = tl >> 5;  // ks 0..3
        float acc = 0.f;
        const float* hrow = p.h + r * H_ + ks * 128;
        const float* wcol = p.W_fc + ks * 128 * O_ + o;
        #pragma unroll 8
        for (int k = 0; k < 128; k += 2) {
            floatx2 hv = ldf2_(hrow + k);
            acc += hv.x * wcol[k * O_] + hv.y * wcol[(k + 1) * O_];
        }
        sc4[sub][tl] = acc;
        __syncthreads();
        if (ks == 0)
            p.out[r * O_ + o] = acc + sc4[sub][o + 32] + sc4[sub][o + 64] +
                                sc4[sub][o + 96] + p.b_fc[o];
    }
}

extern "C" void kernel_launch(void* const* d_in, const int* in_sizes, int n_in,
                              void* d_out, int out_size, void* d_ws,
                              size_t ws_size, hipStream_t stream) {
    (void)in_sizes; (void)n_in; (void)out_size; (void)ws_size;
    P p;
    p.x = (const float*)d_in[0];
    p.dts = (const float*)d_in[1];
    p.Wq = (const float*)d_in[2];
    p.bq = (const float*)d_in[3];
    const float* Wk = (const float*)d_in[4];
    p.bk = (const float*)d_in[5];
    const float* Wv = (const float*)d_in[6];
    p.bv = (const float*)d_in[7];
    const float* W_gd = (const float*)d_in[8];
    p.b_gd = (const float*)d_in[9];
    const float* W_tau = (const float*)d_in[10];
    p.b_tau = (const float*)d_in[11];
    p.gleak = (const float*)d_in[12];
    p.cm = (const float*)d_in[13];
    p.W_fc = (const float*)d_in[14];
    p.b_fc = (const float*)d_in[15];
    p.out = (float*)d_out;

    float* ws = (float*)d_ws;
    p.h = ws;                            // B*H fp32
    p.ctx = p.h + B_ * H_;               // B*A fp32
    p.Kpart = p.ctx + B_ * A_;           // 128 blocks*16 rows*128 fp32
    p.Vpart = p.Kpart + 262144;
    unsigned short* Wpack = (unsigned short*)(p.Vpart + 262144);
    p.Wy = Wpack;                        // 786432 ushorts
    p.Wx = Wpack + 786432;               // 65536
    p.Wc = Wpack + 851968;               // 131072
    p.Wkv = Wpack + 983040;              // 131072
    p.hpack = Wpack + 1114112;           // B*H ushorts
    p.yapack = p.hpack + B_ * H_;
    p.ybpack = p.yapack + B_ * H_;
    p.Kh = p.ybpack + B_ * H_;           // B*T*A bf16
    p.Vh = p.Kh + (size_t)B_ * T_ * A_;  // B*A*T bf16 (transposed)
    p.bar = (unsigned*)(p.Vh + (size_t)B_ * T_ * A_);  // 512 uints

    init_kernel<<<512, 256, 0, stream>>>(p.hpack, p.bar);
    pack_w_kernel<<<4352, 256, 0, stream>>>(W_gd, W_tau, Wk, Wv, Wpack);

    // 128 blocks x 256 threads (4 waves). __launch_bounds__(256,1) -> 4
    // waves/CU -> 512-VGPR budget: the 60 weight fragments (240 VGPRs) stay
    // register-resident (R5/R6 spilled at the 128-VGPR cap from 2-blocks/CU
    // launch bounds). Stage GEMMs therefore do ZERO weight memory traffic.
    // 128 blocks <= 256 CUs -> all co-resident -> fence-free MALL barrier safe.
    fused_kernel<<<dim3(128), dim3(256), 0, stream>>>(p);
}

// Round 9
// 4746.717 us; speedup vs baseline: 2.6119x; 1.0074x over previous
//
#include <hip/hip_runtime.h>
#include <math.h>

#define B_ 256
#define T_ 128
#define D_ 64
#define H_ 512
#define A_ 128
#define O_ 32

typedef __attribute__((ext_vector_type(8))) short short8;
typedef __attribute__((ext_vector_type(8))) unsigned short ushort8;
typedef __attribute__((ext_vector_type(4))) float floatx4;
typedef __attribute__((ext_vector_type(2))) float floatx2;

__device__ __forceinline__ float sp_(float x) {
    return fmaxf(x, 0.f) + log1pf(expf(-fabsf(x)));
}
__device__ __forceinline__ float sigm_(float x) {
    return 1.f / (1.f + expf(-x));
}
__device__ __forceinline__ unsigned short f2bf_(float f) {
    unsigned int u = __float_as_uint(f);
    return (unsigned short)((u + 0x7FFFu + ((u >> 16) & 1u)) >> 16);
}
__device__ __forceinline__ float bf2f_(unsigned short u) {
    return __uint_as_float(((unsigned)u) << 16);
}

// ---- coherent (MALL-level, no-fence) accessors for cross-block data --------
__device__ __forceinline__ void st16_(unsigned short* p, unsigned short v) {
    __hip_atomic_store(p, v, __ATOMIC_RELAXED, __HIP_MEMORY_SCOPE_SYSTEM);
}
__device__ __forceinline__ void stf_(float* p, float v) {
    __hip_atomic_store(p, v, __ATOMIC_RELAXED, __HIP_MEMORY_SCOPE_SYSTEM);
}
__device__ __forceinline__ float ldf_(const float* p) {
    return __hip_atomic_load(p, __ATOMIC_RELAXED, __HIP_MEMORY_SCOPE_SYSTEM);
}
__device__ __forceinline__ unsigned long long ld64_(const unsigned long long* p) {
    return __hip_atomic_load(p, __ATOMIC_RELAXED, __HIP_MEMORY_SCOPE_SYSTEM);
}
__device__ __forceinline__ floatx2 ldf2_(const float* p) {
    unsigned long long u = ld64_((const unsigned long long*)p);
    union { unsigned long long u; floatx2 f; } c;
    c.u = u;
    return c.f;
}

// ---------------- init: hpack = 0, flags = 0 --------------------------------
__global__ void init_kernel(unsigned short* __restrict__ hpack,
                            unsigned* __restrict__ bar) {
    int i = blockIdx.x * 256 + threadIdx.x;
    if (i < B_ * H_) hpack[i] = 0;
    if (i < 8192) bar[i] = 0u;
}

// -------- pack all weights into MFMA B-frag bf16 order ----------------------
__global__ void pack_w_kernel(const float* __restrict__ W_gd,
                              const float* __restrict__ W_tau,
                              const float* __restrict__ Wk,
                              const float* __restrict__ Wv,
                              unsigned short* __restrict__ Wpack) {
    int gid = blockIdx.x * 256 + threadIdx.x;
    if (gid >= 1114112) return;
    int j = gid & 7;
    int l = (gid >> 3) & 63;
    int kpart = (l >> 4) * 8 + j;
    int npart = l & 15;
    float v;
    if (gid < 786432) {
        int f = gid >> 9;
        int s = f % 3;
        int rem = f / 3;
        int kb = rem & 15, ct = rem >> 4;
        int k = kb * 32 + kpart;
        int c = ct * 16 + npart;
        if (s == 0)      v = W_gd[(size_t)(D_ + k) * 1024 + c];
        else if (s == 1) v = W_gd[(size_t)(D_ + k) * 1024 + 512 + c];
        else             v = W_tau[(size_t)k * 512 + c];
    } else if (gid < 851968) {
        int r = gid - 786432;
        int f = r >> 9;
        int s = f & 1, kb = (f >> 1) & 1, ct = f >> 2;
        int k = kb * 32 + kpart;
        int c = ct * 16 + npart;
        v = W_gd[(size_t)k * 1024 + s * 512 + c];
    } else if (gid < 983040) {
        int r = gid - 851968;
        int f = r >> 9;
        int s = f & 1, kb = (f >> 1) & 3, ct = f >> 3;
        int k = kb * 32 + kpart;
        int c = ct * 16 + npart;
        v = W_gd[(size_t)(D_ + H_ + k) * 1024 + s * 512 + c];
    } else {
        int r = gid - 983040;
        int f = r >> 9;
        int kb = f & 15, c4 = f >> 4;
        int k = kb * 32 + kpart;
        int n = (c4 & 7) * 16 + npart;
        v = (c4 < 8) ? Wk[(size_t)k * A_ + n] : Wv[(size_t)k * A_ + n];
    }
    Wpack[gid] = f2bf_(v);
}

// ---- group barrier: 8 blocks, per-block flag slots (NO shared-line RMW) ----
// Each block stores its own monotonically increasing phase counter to its own
// cacheline; 8 threads poll the 8 slots in parallel. Zero atomic contention.
__device__ __forceinline__ void gsyncF(unsigned* flags, int j, unsigned cnt) {
    __syncthreads();  // compiler emits vmcnt(0) drain: data stores are at MALL
    if (threadIdx.x == 0)
        __hip_atomic_store(flags + j * 64, cnt, __ATOMIC_RELAXED,
                           __HIP_MEMORY_SCOPE_SYSTEM);
    if (threadIdx.x < 8) {
        while (__hip_atomic_load(flags + threadIdx.x * 64, __ATOMIC_RELAXED,
                                 __HIP_MEMORY_SCOPE_SYSTEM) < cnt) {
            __builtin_amdgcn_s_sleep(1);
        }
    }
    __syncthreads();
}

struct P {
    const float *x, *dts, *Wq, *bq, *bk, *bv, *b_gd, *b_tau, *gleak, *cm,
        *W_fc, *b_fc;
    float *h, *ctx, *out, *Kpart, *Vpart;
    unsigned short *Kh, *Vh;  // K: [B][T][A] bf16 ; V: [B][A][T] bf16
    const unsigned short *Wy, *Wx, *Wc, *Wkv;
    unsigned short *hpack, *yapack, *ybpack;
    unsigned* bar;
};

__global__ __launch_bounds__(256, 1) void fused_kernel(P p) {
    const int tid = threadIdx.x;
    const int bid = blockIdx.x;
    const int lane = tid & 63;
    const int wave = tid >> 6;            // 0..3
    const int g = bid & 15;               // group of 8 blocks (bid%8 -> XCD)
    const int j = bid >> 4;               // block within group 0..7
    const int ct = j * 4 + wave;          // channel strip 0..31
    const int m_tile = g;                 // batch tile (16 rows)
    unsigned* flags = p.bar + g * 512;    // 8 slots x 64 uints (256B apart)
    unsigned cnt = 0;                     // this block's phase counter

    __shared__ float WqL[D_ * 129];
    __shared__ float xs4[2][D_];
    __shared__ float q4[2][A_];
    __shared__ float sc4[2][T_];
    __shared__ float red[2][2];
    __shared__ unsigned short AsL[16 * 512];  // 16 KB staged A (one m-tile)
    __shared__ unsigned short As2[2 * 512];   // 2 KB h A-frags for kv partial

    const int quad = lane >> 4;
    const int c = ct * 16 + (lane & 15);
    const float btau = p.b_tau[c];
    const float lk = sp_(p.cm[c]) + sp_(p.gleak[c]) + 1e-6f;
    const float bgd_g = p.b_gd[c];
    const float bgd_d = p.b_gd[512 + c];
    const int lane_p = ((c >> 3) & 3) * 16;
    const int pbase = (m_tile * 16 + (c >> 5)) * 512 + (c & 7);

    const int sub = tid >> 7;             // 0..1
    const int tl = tid & 127;
    const int r = g * 16 + j * 2 + sub;   // this block's 2 attention rows
    const int rrow = r & 15;

    // ---- persistent register weights: 48 + 4 + 8 = 60 frags (240 VGPRs) ----
    short8 wg[16], wd[16], wt[16];
    short8 wxg[2], wxd[2], wcg[4], wcd[4];
    {
        const short8* Wy8 = (const short8*)p.Wy;
        #pragma unroll
        for (int kb = 0; kb < 16; ++kb) {
            wg[kb] = Wy8[((ct * 16 + kb) * 3 + 0) * 64 + lane];
            wd[kb] = Wy8[((ct * 16 + kb) * 3 + 1) * 64 + lane];
            wt[kb] = Wy8[((ct * 16 + kb) * 3 + 2) * 64 + lane];
        }
        const short8* Wx8 = (const short8*)p.Wx;
        const short8* Wc8 = (const short8*)p.Wc;
        #pragma unroll
        for (int kb = 0; kb < 2; ++kb) {
            wxg[kb] = Wx8[((ct * 2 + kb) * 2 + 0) * 64 + lane];
            wxd[kb] = Wx8[((ct * 2 + kb) * 2 + 1) * 64 + lane];
        }
        #pragma unroll
        for (int kb = 0; kb < 4; ++kb) {
            wcg[kb] = Wc8[((ct * 4 + kb) * 2 + 0) * 64 + lane];
            wcd[kb] = Wc8[((ct * 4 + kb) * 2 + 1) * 64 + lane];
        }
    }

    for (int i = tid; i < D_ * A_; i += 256) {
        int d = i >> 7, a = i & 127;
        WqL[d * 129 + a] = p.Wq[i];
    }

    floatx4 hreg = {0.f, 0.f, 0.f, 0.f};
    floatx4 rk1, rk2, rk3, baseg, based, ycur, dt4;

    const short8* Wkv8 = (const short8*)p.Wkv;

    __syncthreads();  // WqL ready

    for (int t = 0; t < T_; ++t) {
        // ---------- phase A: K/V merge of t-1 + attention (2 rows) ----------
        {
            if (t > 0) {
                float ks = p.bk[tl], vs = p.bv[tl];
                #pragma unroll
                for (int jj = 0; jj < 8; ++jj) {
                    ks += ldf_(p.Kpart + ((g * 8 + jj) * 16 + rrow) * 128 + tl);
                    vs += ldf_(p.Vpart + ((g * 8 + jj) * 16 + rrow) * 128 + tl);
                }
                p.Kh[(size_t)(r * T_ + (t - 1)) * A_ + tl] = f2bf_(ks);
                p.Vh[((size_t)r * A_ + tl) * T_ + (t - 1)] = f2bf_(vs);
            }
            if (tl < 16)
                ((float4*)xs4[sub])[tl] =
                    ((const float4*)&p.x[(r * T_ + t) * D_])[tl];
            __syncthreads();
            float qa = p.bq[tl];
            #pragma unroll 8
            for (int d = 0; d < D_; ++d) qa += xs4[sub][d] * WqL[d * 129 + tl];
            q4[sub][tl] = qa;
            __syncthreads();
            if (t == 0) {
                stf_(p.ctx + r * A_ + tl, 0.f);
            } else {
                const float rscale = 0.08838834764831845f;  // 1/sqrt(128)
                const int grp = tl >> 4, ln = tl & 15;
                float qv[8];
                #pragma unroll
                for (int i = 0; i < 8; ++i) qv[i] = q4[sub][ln * 8 + i];
                for (int s = grp; s < t; s += 8) {
                    ushort8 k8 = *((const ushort8*)(p.Kh +
                                     (size_t)(r * T_ + s) * A_) + ln);
                    float a2 = 0.f;
                    #pragma unroll
                    for (int i = 0; i < 8; ++i) a2 += bf2f_(k8[i]) * qv[i];
                    #pragma unroll
                    for (int off = 8; off > 0; off >>= 1)
                        a2 += __shfl_xor(a2, off, 16);
                    if (ln == 0) sc4[sub][s] = a2 * rscale;
                }
                __syncthreads();
                float mloc = -1e30f;
                for (int s = tl; s < t; s += 128) mloc = fmaxf(mloc, sc4[sub][s]);
                #pragma unroll
                for (int off = 32; off > 0; off >>= 1)
                    mloc = fmaxf(mloc, __shfl_xor(mloc, off, 64));
                if (lane == 0) red[sub][wave & 1] = mloc;
                __syncthreads();
                float m = fmaxf(red[sub][0], red[sub][1]);
                float ssum = 0.f;
                for (int s = tl; s < t; s += 128) {
                    float e = expf(sc4[sub][s] - m);
                    sc4[sub][s] = e;
                    ssum += e;
                }
                #pragma unroll
                for (int off = 32; off > 0; off >>= 1)
                    ssum += __shfl_xor(ssum, off, 64);
                __syncthreads();
                if (lane == 0) red[sub][wave & 1] = ssum;
                __syncthreads();
                float rs = 1.f / (red[sub][0] + red[sub][1]);
                const unsigned short* Vrow = p.Vh + (size_t)(r * A_ + tl) * T_;
                float ca0 = 0.f, ca1 = 0.f;
                int s0 = 0;
                for (; s0 + 16 <= t; s0 += 16) {
                    ushort8 v0 = *(const ushort8*)(Vrow + s0);
                    ushort8 v1 = *(const ushort8*)(Vrow + s0 + 8);
                    #pragma unroll
                    for (int i = 0; i < 8; ++i) {
                        ca0 += sc4[sub][s0 + i] * bf2f_(v0[i]);
                        ca1 += sc4[sub][s0 + 8 + i] * bf2f_(v1[i]);
                    }
                }
                if (s0 + 8 <= t) {
                    ushort8 v0 = *(const ushort8*)(Vrow + s0);
                    #pragma unroll
                    for (int i = 0; i < 8; ++i)
                        ca0 += sc4[sub][s0 + i] * bf2f_(v0[i]);
                    s0 += 8;
                }
                for (; s0 < t; ++s0) ca0 += sc4[sub][s0] * bf2f_(Vrow[s0]);
                stf_(p.ctx + r * A_ + tl, (ca0 + ca1) * rs);
            }
        }
        gsyncF(flags, j, ++cnt);

        // ---------- phase B: stage1 + base fold (register weights) ----------
        {
            {
                const unsigned long long* src =
                    (const unsigned long long*)p.hpack + m_tile * 2048;
                unsigned long long* dst = (unsigned long long*)AsL;
                #pragma unroll
                for (int i = 0; i < 8; ++i)
                    dst[tid + i * 256] = ld64_(src + tid + i * 256);
            }
            __syncthreads();

            const int mrow = lane & 15;
            const int kq = lane >> 4;
            #pragma unroll
            for (int i = 0; i < 4; ++i)
                dt4[i] = p.dts[(m_tile * 16 + quad * 4 + i) * T_ + t];

            floatx4 bg = {0.f, 0.f, 0.f, 0.f};
            floatx4 bd = {0.f, 0.f, 0.f, 0.f};
            const float4* xrow =
                (const float4*)&p.x[((m_tile * 16 + mrow) * T_ + t) * D_];
            #pragma unroll
            for (int kb = 0; kb < 2; ++kb) {
                float4 u = xrow[kb * 8 + kq * 2], v = xrow[kb * 8 + kq * 2 + 1];
                short8 ax;
                ax[0] = (short)f2bf_(u.x); ax[1] = (short)f2bf_(u.y);
                ax[2] = (short)f2bf_(u.z); ax[3] = (short)f2bf_(u.w);
                ax[4] = (short)f2bf_(v.x); ax[5] = (short)f2bf_(v.y);
                ax[6] = (short)f2bf_(v.z); ax[7] = (short)f2bf_(v.w);
                bg = __builtin_amdgcn_mfma_f32_16x16x32_bf16(ax, wxg[kb], bg, 0, 0, 0);
                bd = __builtin_amdgcn_mfma_f32_16x16x32_bf16(ax, wxd[kb], bd, 0, 0, 0);
            }
            const float* crow = &p.ctx[(m_tile * 16 + mrow) * A_];
            #pragma unroll
            for (int kb = 0; kb < 4; ++kb) {
                short8 ac;
                #pragma unroll
                for (int q2 = 0; q2 < 4; ++q2) {
                    floatx2 f = ldf2_(crow + kb * 32 + kq * 8 + q2 * 2);
                    ac[q2 * 2] = (short)f2bf_(f.x);
                    ac[q2 * 2 + 1] = (short)f2bf_(f.y);
                }
                bg = __builtin_amdgcn_mfma_f32_16x16x32_bf16(ac, wcg[kb], bg, 0, 0, 0);
                bd = __builtin_amdgcn_mfma_f32_16x16x32_bf16(ac, wcd[kb], bd, 0, 0, 0);
            }
            floatx4 ag = {0.f, 0.f, 0.f, 0.f};
            floatx4 ad = {0.f, 0.f, 0.f, 0.f};
            floatx4 at = {0.f, 0.f, 0.f, 0.f};
            #pragma unroll
            for (int kb = 0; kb < 16; ++kb) {
                short8 a = *(const short8*)(AsL + (kb * 64 + lane) * 8);
                ag = __builtin_amdgcn_mfma_f32_16x16x32_bf16(a, wg[kb], ag, 0, 0, 0);
                ad = __builtin_amdgcn_mfma_f32_16x16x32_bf16(a, wd[kb], ad, 0, 0, 0);
                at = __builtin_amdgcn_mfma_f32_16x16x32_bf16(a, wt[kb], at, 0, 0, 0);
            }
            #pragma unroll
            for (int i = 0; i < 4; ++i) {
                baseg[i] = bg[i] + bgd_g;
                based[i] = bd[i] + bgd_d;
                float gate = ag[i] + baseg[i];
                float dyn = ad[i] + based[i];
                float tau = sp_(at[i] + btau);
                float ki = (sigm_(gate) * tanhf(dyn) - hreg[i]) / (tau + lk);
                rk1[i] = ki;
                float yn = hreg[i] + dt4[i] * ki * (1.f / 3.f);
                ycur[i] = yn;
                st16_(p.yapack + pbase + (lane_p + (quad * 4 + i)) * 8, f2bf_(yn));
            }
        }
        gsyncF(flags, j, ++cnt);

        // ---------- stages 2..4 ----------
        #pragma unroll 1
        for (int stage = 2; stage <= 4; ++stage) {
            const unsigned short* ysrc =
                (stage == 2) ? p.yapack : (stage == 3) ? p.ybpack : p.yapack;
            unsigned short* ydst =
                (stage == 2) ? p.ybpack : (stage == 3) ? p.yapack : p.hpack;
            {
                const unsigned long long* src =
                    (const unsigned long long*)ysrc + m_tile * 2048;
                unsigned long long* dst = (unsigned long long*)AsL;
                #pragma unroll
                for (int i = 0; i < 8; ++i)
                    dst[tid + i * 256] = ld64_(src + tid + i * 256);
            }
            __syncthreads();
            floatx4 ag = {0.f, 0.f, 0.f, 0.f};
            floatx4 ad = {0.f, 0.f, 0.f, 0.f};
            floatx4 at = {0.f, 0.f, 0.f, 0.f};
            #pragma unroll
            for (int kb = 0; kb < 16; ++kb) {
                short8 a = *(const short8*)(AsL + (kb * 64 + lane) * 8);
                ag = __builtin_amdgcn_mfma_f32_16x16x32_bf16(a, wg[kb], ag, 0, 0, 0);
                ad = __builtin_amdgcn_mfma_f32_16x16x32_bf16(a, wd[kb], ad, 0, 0, 0);
                at = __builtin_amdgcn_mfma_f32_16x16x32_bf16(a, wt[kb], at, 0, 0, 0);
            }
            #pragma unroll
            for (int i = 0; i < 4; ++i) {
                float gate = ag[i] + baseg[i];
                float dyn = ad[i] + based[i];
                float tau = sp_(at[i] + btau);
                float ki = (sigm_(gate) * tanhf(dyn) - ycur[i]) / (tau + lk);
                float yn;
                if (stage == 2) {
                    rk2[i] = ki;
                    yn = hreg[i] + dt4[i] * (ki - rk1[i] * (1.f / 3.f));
                } else if (stage == 3) {
                    rk3[i] = ki;
                    yn = hreg[i] + dt4[i] * (rk1[i] - rk2[i] + ki);
                } else {
                    yn = hreg[i] +
                         dt4[i] * (rk1[i] + 3.f * rk2[i] + 3.f * rk3[i] + ki) * 0.125f;
                    hreg[i] = yn;
                }
                ycur[i] = yn;
                st16_(ydst + pbase + (lane_p + (quad * 4 + i)) * 8, f2bf_(yn));
            }
            if (stage == 4) {
                // block-local h A-frags (this block's 2 kb strips)
                const int lbase = (wave >> 1) * 512 + (c & 7);
                #pragma unroll
                for (int i = 0; i < 4; ++i)
                    As2[lbase + (lane_p + (quad * 4 + i)) * 8] = f2bf_(hreg[i]);
                __syncthreads();
                // partial K/V over this block's K-range
                #pragma unroll
                for (int h4 = 0; h4 < 4; ++h4) {
                    const int c4 = wave + h4 * 4;  // 0..15 (0..7=K, 8..15=V)
                    floatx4 acc = {0.f, 0.f, 0.f, 0.f};
                    #pragma unroll
                    for (int kk = 0; kk < 2; ++kk) {
                        short8 a = *(const short8*)(As2 + (kk * 64 + lane) * 8);
                        acc = __builtin_amdgcn_mfma_f32_16x16x32_bf16(
                            a, Wkv8[(c4 * 16 + (j * 2 + kk)) * 64 + lane], acc,
                            0, 0, 0);
                    }
                    const int ac = (c4 & 7) * 16 + (lane & 15);
                    float* part = (c4 < 8) ? p.Kpart : p.Vpart;
                    #pragma unroll
                    for (int i = 0; i < 4; ++i)
                        stf_(part + ((g * 8 + j) * 16 + quad * 4 + i) * 128 + ac,
                             acc[i]);
                }
            }
            gsyncF(flags, j, ++cnt);
        }
    }

    // ---------- write final h, then fc ----------
    #pragma unroll
    for (int i = 0; i < 4; ++i)
        stf_(p.h + (m_tile * 16 + quad * 4 + i) * H_ + c, hreg[i]);
    gsyncF(flags, j, ++cnt);
    {
        const int o = tl & 31, ks = tl >> 5;  // ks 0..3
        float acc = 0.f;
        const float* hrow = p.h + r * H_ + ks * 128;
        const float* wcol = p.W_fc + ks * 128 * O_ + o;
        #pragma unroll 8
        for (int k = 0; k < 128; k += 2) {
            floatx2 hv = ldf2_(hrow + k);
            acc += hv.x * wcol[k * O_] + hv.y * wcol[(k + 1) * O_];
        }
        sc4[sub][tl] = acc;
        __syncthreads();
        if (ks == 0)
            p.out[r * O_ + o] = acc + sc4[sub][o + 32] + sc4[sub][o + 64] +
                                sc4[sub][o + 96] + p.b_fc[o];
    }
}

extern "C" void kernel_launch(void* const* d_in, const int* in_sizes, int n_in,
                              void* d_out, int out_size, void* d_ws,
                              size_t ws_size, hipStream_t stream) {
    (void)in_sizes; (void)n_in; (void)out_size; (void)ws_size;
    P p;
    p.x = (const float*)d_in[0];
    p.dts = (const float*)d_in[1];
    p.Wq = (const float*)d_in[2];
    p.bq = (const float*)d_in[3];
    const float* Wk = (const float*)d_in[4];
    p.bk = (const float*)d_in[5];
    const float* Wv = (const float*)d_in[6];
    p.bv = (const float*)d_in[7];
    const float* W_gd = (const float*)d_in[8];
    p.b_gd = (const float*)d_in[9];
    const float* W_tau = (const float*)d_in[10];
    p.b_tau = (const float*)d_in[11];
    p.gleak = (const float*)d_in[12];
    p.cm = (const float*)d_in[13];
    p.W_fc = (const float*)d_in[14];
    p.b_fc = (const float*)d_in[15];
    p.out = (float*)d_out;

    float* ws = (float*)d_ws;
    p.h = ws;                            // B*H fp32
    p.ctx = p.h + B_ * H_;               // B*A fp32
    p.Kpart = p.ctx + B_ * A_;           // 128 blocks*16 rows*128 fp32
    p.Vpart = p.Kpart + 262144;
    unsigned short* Wpack = (unsigned short*)(p.Vpart + 262144);
    p.Wy = Wpack;                        // 786432 ushorts
    p.Wx = Wpack + 786432;               // 65536
    p.Wc = Wpack + 851968;               // 131072
    p.Wkv = Wpack + 983040;              // 131072
    p.hpack = Wpack + 1114112;           // B*H ushorts
    p.yapack = p.hpack + B_ * H_;
    p.ybpack = p.yapack + B_ * H_;
    p.Kh = p.ybpack + B_ * H_;           // B*T*A bf16
    p.Vh = p.Kh + (size_t)B_ * T_ * A_;  // B*A*T bf16 (transposed)
    p.bar = (unsigned*)(p.Vh + (size_t)B_ * T_ * A_);  // 8192 uints (flags)

    init_kernel<<<512, 256, 0, stream>>>(p.hpack, p.bar);
    pack_w_kernel<<<4352, 256, 0, stream>>>(W_gd, W_tau, Wk, Wv, Wpack);

    // 128 blocks x 256 threads (4 waves), launch_bounds(256,1): 512-VGPR
    // budget keeps the 60 weight fragments register-resident (VGPR=236, R8).
    // Barrier: per-block flag slots on separate cachelines (no shared-line
    // RMW serialization); data exchange via MALL-coherent sc accesses.
    fused_kernel<<<dim3(128), dim3(256), 0, stream>>>(p);
}

// Round 10
// 4631.614 us; speedup vs baseline: 2.6768x; 1.0249x over previous
//
#include <hip/hip_runtime.h>
#include <math.h>

#define B_ 256
#define T_ 128
#define D_ 64
#define H_ 512
#define A_ 128
#define O_ 32

typedef __attribute__((ext_vector_type(8))) short short8;
typedef __attribute__((ext_vector_type(8))) unsigned short ushort8;
typedef __attribute__((ext_vector_type(4))) float floatx4;
typedef __attribute__((ext_vector_type(2))) float floatx2;
typedef unsigned long long ull;

__device__ __forceinline__ float sp_(float x) {
    return fmaxf(x, 0.f) + log1pf(expf(-fabsf(x)));
}
__device__ __forceinline__ float sigm_(float x) {
    return 1.f / (1.f + expf(-x));
}
__device__ __forceinline__ unsigned short f2bf_(float f) {
    unsigned int u = __float_as_uint(f);
    return (unsigned short)((u + 0x7FFFu + ((u >> 16) & 1u)) >> 16);
}
__device__ __forceinline__ float bf2f_(unsigned short u) {
    return __uint_as_float(((unsigned)u) << 16);
}

// ---- coherent (MALL-level, no-fence) accessors for cross-block data --------
__device__ __forceinline__ void stf_(float* p, float v) {
    __hip_atomic_store(p, v, __ATOMIC_RELAXED, __HIP_MEMORY_SCOPE_SYSTEM);
}
__device__ __forceinline__ float ldf_(const float* p) {
    return __hip_atomic_load(p, __ATOMIC_RELAXED, __HIP_MEMORY_SCOPE_SYSTEM);
}
__device__ __forceinline__ void st64_(ull* p, ull v) {
    __hip_atomic_store(p, v, __ATOMIC_RELAXED, __HIP_MEMORY_SCOPE_SYSTEM);
}
__device__ __forceinline__ ull ld64_(const ull* p) {
    return __hip_atomic_load(p, __ATOMIC_RELAXED, __HIP_MEMORY_SCOPE_SYSTEM);
}
__device__ __forceinline__ floatx2 ldf2_(const float* p) {
    union { ull u; floatx2 f; } c;
    c.u = ld64_((const ull*)p);
    return c.f;
}

// ---------------- init: hpack = 0, flags = 0 --------------------------------
__global__ void init_kernel(unsigned short* __restrict__ hpack,
                            unsigned* __restrict__ bar) {
    int i = blockIdx.x * 256 + threadIdx.x;
    if (i < B_ * H_) hpack[i] = 0;
    if (i < 8192) bar[i] = 0u;
}

// -------- pack all weights into MFMA B-frag bf16 order ----------------------
__global__ void pack_w_kernel(const float* __restrict__ W_gd,
                              const float* __restrict__ W_tau,
                              const float* __restrict__ Wk,
                              const float* __restrict__ Wv,
                              unsigned short* __restrict__ Wpack) {
    int gid = blockIdx.x * 256 + threadIdx.x;
    if (gid >= 1114112) return;
    int j = gid & 7;
    int l = (gid >> 3) & 63;
    int kpart = (l >> 4) * 8 + j;
    int npart = l & 15;
    float v;
    if (gid < 786432) {
        int f = gid >> 9;
        int s = f % 3;
        int rem = f / 3;
        int kb = rem & 15, ct = rem >> 4;
        int k = kb * 32 + kpart;
        int c = ct * 16 + npart;
        if (s == 0)      v = W_gd[(size_t)(D_ + k) * 1024 + c];
        else if (s == 1) v = W_gd[(size_t)(D_ + k) * 1024 + 512 + c];
        else             v = W_tau[(size_t)k * 512 + c];
    } else if (gid < 851968) {
        int r = gid - 786432;
        int f = r >> 9;
        int s = f & 1, kb = (f >> 1) & 1, ct = f >> 2;
        int k = kb * 32 + kpart;
        int c = ct * 16 + npart;
        v = W_gd[(size_t)k * 1024 + s * 512 + c];
    } else if (gid < 983040) {
        int r = gid - 851968;
        int f = r >> 9;
        int s = f & 1, kb = (f >> 1) & 3, ct = f >> 3;
        int k = kb * 32 + kpart;
        int c = ct * 16 + npart;
        v = W_gd[(size_t)(D_ + H_ + k) * 1024 + s * 512 + c];
    } else {
        int r = gid - 983040;
        int f = r >> 9;
        int kb = f & 15, c4 = f >> 4;
        int k = kb * 32 + kpart;
        int n = (c4 & 7) * 16 + npart;
        v = (c4 < 8) ? Wk[(size_t)k * A_ + n] : Wv[(size_t)k * A_ + n];
    }
    Wpack[gid] = f2bf_(v);
}

// ---- group barrier: 8 blocks, per-block flag slots (no shared-line RMW) ----
__device__ __forceinline__ void gsyncF(unsigned* flags, int j, unsigned cnt) {
    __syncthreads();  // per-wave vmcnt(0) drain: data stores are at MALL
    if (threadIdx.x == 0)
        __hip_atomic_store(flags + j * 64, cnt, __ATOMIC_RELAXED,
                           __HIP_MEMORY_SCOPE_SYSTEM);
    if (threadIdx.x < 8) {
        while (__hip_atomic_load(flags + threadIdx.x * 64, __ATOMIC_RELAXED,
                                 __HIP_MEMORY_SCOPE_SYSTEM) < cnt) {
            __builtin_amdgcn_s_sleep(1);
        }
    }
    __syncthreads();
}

struct P {
    const float *x, *dts, *Wq, *bq, *bk, *bv, *b_gd, *b_tau, *gleak, *cm,
        *W_fc, *b_fc;
    float *h, *ctx, *out, *Kpart, *Vpart;
    unsigned short* Kh;  // K: [B][T][A] bf16 (block-private rows, plain ld/st)
    const unsigned short *Wy, *Wx, *Wc, *Wkv;
    unsigned short *hpack, *yapack, *ybpack;  // layout [m_tile][strip][row][col]
    unsigned* bar;
};

__global__ __launch_bounds__(256, 1) void fused_kernel(P p) {
    const int tid = threadIdx.x;
    const int bid = blockIdx.x;
    const int lane = tid & 63;
    const int wave = tid >> 6;            // 0..3
    const int g = bid & 15;               // group of 8 blocks (bid%8 -> XCD)
    const int j = bid >> 4;               // block within group 0..7
    const int ct = j * 4 + wave;          // channel strip 0..31
    unsigned* flags = p.bar + g * 512;    // 8 slots x 64 uints (256B apart)
    unsigned cnt = 0;

    __shared__ float WqL[D_ * 129];
    __shared__ float xs4[2][D_];
    __shared__ float q4[2][A_];
    __shared__ float sc4[2][T_];
    __shared__ float red[2][2];
    __shared__ unsigned short AsL[32 * 256];      // 16 KB staged A (one m_tile)
    __shared__ unsigned short ypbuf[4 * 256];     // 2 KB out-tile transpose
    __shared__ unsigned short As2[2 * 512];       // 2 KB h A-frags for kv
    __shared__ unsigned short VhL[2][A_][136];    // ~70 KB V history (LDS!)

    const int quad = lane >> 4;
    const int c = ct * 16 + (lane & 15);
    const float btau = p.b_tau[c];
    const float lk = sp_(p.cm[c]) + sp_(p.gleak[c]) + 1e-6f;
    const float bgd_g = p.b_gd[c];
    const float bgd_d = p.b_gd[512 + c];
    // new-layout A-frag read offset within AsL (ushort idx)
    const int aoff = (quad >> 1) * 256 + (lane & 15) * 16 + (quad & 1) * 8;
    // out-tile LDS transpose write base
    const int ypw = wave * 256 + (lane & 15);

    const int sub = tid >> 7;             // 0..1
    const int tl = tid & 127;
    const int r = g * 16 + j * 2 + sub;   // this block's 2 attention rows
    const int rrow = r & 15;

    // ---- persistent register weights: 60 frags (240 VGPRs) ----
    short8 wg[16], wd[16], wt[16];
    short8 wxg[2], wxd[2], wcg[4], wcd[4];
    {
        const short8* Wy8 = (const short8*)p.Wy;
        #pragma unroll
        for (int kb = 0; kb < 16; ++kb) {
            wg[kb] = Wy8[((ct * 16 + kb) * 3 + 0) * 64 + lane];
            wd[kb] = Wy8[((ct * 16 + kb) * 3 + 1) * 64 + lane];
            wt[kb] = Wy8[((ct * 16 + kb) * 3 + 2) * 64 + lane];
        }
        const short8* Wx8 = (const short8*)p.Wx;
        const short8* Wc8 = (const short8*)p.Wc;
        #pragma unroll
        for (int kb = 0; kb < 2; ++kb) {
            wxg[kb] = Wx8[((ct * 2 + kb) * 2 + 0) * 64 + lane];
            wxd[kb] = Wx8[((ct * 2 + kb) * 2 + 1) * 64 + lane];
        }
        #pragma unroll
        for (int kb = 0; kb < 4; ++kb) {
            wcg[kb] = Wc8[((ct * 4 + kb) * 2 + 0) * 64 + lane];
            wcd[kb] = Wc8[((ct * 4 + kb) * 2 + 1) * 64 + lane];
        }
    }

    for (int i = tid; i < D_ * A_; i += 256) {
        int d = i >> 7, a = i & 127;
        WqL[d * 129 + a] = p.Wq[i];
    }

    floatx4 hreg = {0.f, 0.f, 0.f, 0.f};
    floatx4 rk1, rk2, rk3, baseg, based, ycur, dt4;

    const short8* Wkv8 = (const short8*)p.Wkv;
    const ull* hp_qw = (const ull*)p.hpack;
    const ull* ya_qw = (const ull*)p.yapack;
    const ull* yb_qw = (const ull*)p.ybpack;

    __syncthreads();  // WqL ready

    for (int t = 0; t < T_; ++t) {
        // ---------- phase A: K/V merge of t-1 + attention (2 rows) ----------
        {
            if (t > 0) {
                float ks = p.bk[tl], vs = p.bv[tl];
                #pragma unroll
                for (int jj = 0; jj < 8; ++jj) {
                    ks += ldf_(p.Kpart + ((g * 8 + jj) * 16 + rrow) * 128 + tl);
                    vs += ldf_(p.Vpart + ((g * 8 + jj) * 16 + rrow) * 128 + tl);
                }
                p.Kh[(size_t)(r * T_ + (t - 1)) * A_ + tl] = f2bf_(ks);
                VhL[sub][tl][t - 1] = f2bf_(vs);   // LDS: no global transpose
            }
            if (tl < 16)
                ((float4*)xs4[sub])[tl] =
                    ((const float4*)&p.x[(r * T_ + t) * D_])[tl];
            __syncthreads();
            float qa = p.bq[tl];
            #pragma unroll 8
            for (int d = 0; d < D_; ++d) qa += xs4[sub][d] * WqL[d * 129 + tl];
            q4[sub][tl] = qa;
            __syncthreads();
            if (t == 0) {
                stf_(p.ctx + r * A_ + tl, 0.f);
            } else {
                const float rscale = 0.08838834764831845f;  // 1/sqrt(128)
                const int grp = tl >> 4, ln = tl & 15;
                float qv[8];
                #pragma unroll
                for (int i = 0; i < 8; ++i) qv[i] = q4[sub][ln * 8 + i];
                for (int s = grp; s < t; s += 8) {
                    ushort8 k8 = *((const ushort8*)(p.Kh +
                                     (size_t)(r * T_ + s) * A_) + ln);
                    float a2 = 0.f;
                    #pragma unroll
                    for (int i = 0; i < 8; ++i) a2 += bf2f_(k8[i]) * qv[i];
                    #pragma unroll
                    for (int off = 8; off > 0; off >>= 1)
                        a2 += __shfl_xor(a2, off, 16);
                    if (ln == 0) sc4[sub][s] = a2 * rscale;
                }
                __syncthreads();
                float mloc = -1e30f;
                for (int s = tl; s < t; s += 128) mloc = fmaxf(mloc, sc4[sub][s]);
                #pragma unroll
                for (int off = 32; off > 0; off >>= 1)
                    mloc = fmaxf(mloc, __shfl_xor(mloc, off, 64));
                if (lane == 0) red[sub][wave & 1] = mloc;
                __syncthreads();
                float m = fmaxf(red[sub][0], red[sub][1]);
                float ssum = 0.f;
                for (int s = tl; s < t; s += 128) {
                    float e = expf(sc4[sub][s] - m);
                    sc4[sub][s] = e;
                    ssum += e;
                }
                #pragma unroll
                for (int off = 32; off > 0; off >>= 1)
                    ssum += __shfl_xor(ssum, off, 64);
                __syncthreads();
                if (lane == 0) red[sub][wave & 1] = ssum;
                __syncthreads();
                float rs = 1.f / (red[sub][0] + red[sub][1]);
                const unsigned short* Vrow = &VhL[sub][tl][0];
                float ca0 = 0.f, ca1 = 0.f;
                int s0 = 0;
                for (; s0 + 16 <= t; s0 += 16) {
                    ushort8 v0 = *(const ushort8*)(Vrow + s0);
                    ushort8 v1 = *(const ushort8*)(Vrow + s0 + 8);
                    #pragma unroll
                    for (int i = 0; i < 8; ++i) {
                        ca0 += sc4[sub][s0 + i] * bf2f_(v0[i]);
                        ca1 += sc4[sub][s0 + 8 + i] * bf2f_(v1[i]);
                    }
                }
                if (s0 + 8 <= t) {
                    ushort8 v0 = *(const ushort8*)(Vrow + s0);
                    #pragma unroll
                    for (int i = 0; i < 8; ++i)
                        ca0 += sc4[sub][s0 + i] * bf2f_(v0[i]);
                    s0 += 8;
                }
                for (; s0 < t; ++s0) ca0 += sc4[sub][s0] * bf2f_(Vrow[s0]);
                stf_(p.ctx + r * A_ + tl, (ca0 + ca1) * rs);
            }
        }
        gsyncF(flags, j, ++cnt);

        // ---------- phase B: stage1 + base fold (register weights) ----------
        {
            // stage m_tile's hpack (16 KB, linear layout) -> LDS coalesced
            {
                ull* dst = (ull*)AsL;
                #pragma unroll
                for (int i = 0; i < 8; ++i)
                    dst[tid + i * 256] = ld64_(hp_qw + g * 2048 + tid + i * 256);
            }
            __syncthreads();

            const int mrow = lane & 15;
            const int kq = lane >> 4;
            #pragma unroll
            for (int i = 0; i < 4; ++i)
                dt4[i] = p.dts[(g * 16 + quad * 4 + i) * T_ + t];

            floatx4 bg = {0.f, 0.f, 0.f, 0.f};
            floatx4 bd = {0.f, 0.f, 0.f, 0.f};
            const float4* xrow =
                (const float4*)&p.x[((g * 16 + mrow) * T_ + t) * D_];
            #pragma unroll
            for (int kb = 0; kb < 2; ++kb) {
                float4 u = xrow[kb * 8 + kq * 2], v = xrow[kb * 8 + kq * 2 + 1];
                short8 ax;
                ax[0] = (short)f2bf_(u.x); ax[1] = (short)f2bf_(u.y);
                ax[2] = (short)f2bf_(u.z); ax[3] = (short)f2bf_(u.w);
                ax[4] = (short)f2bf_(v.x); ax[5] = (short)f2bf_(v.y);
                ax[6] = (short)f2bf_(v.z); ax[7] = (short)f2bf_(v.w);
                bg = __builtin_amdgcn_mfma_f32_16x16x32_bf16(ax, wxg[kb], bg, 0, 0, 0);
                bd = __builtin_amdgcn_mfma_f32_16x16x32_bf16(ax, wxd[kb], bd, 0, 0, 0);
            }
            const float* crow = &p.ctx[(g * 16 + mrow) * A_];
            #pragma unroll
            for (int kb = 0; kb < 4; ++kb) {
                short8 ac;
                #pragma unroll
                for (int q2 = 0; q2 < 4; ++q2) {
                    floatx2 f = ldf2_(crow + kb * 32 + kq * 8 + q2 * 2);
                    ac[q2 * 2] = (short)f2bf_(f.x);
                    ac[q2 * 2 + 1] = (short)f2bf_(f.y);
                }
                bg = __builtin_amdgcn_mfma_f32_16x16x32_bf16(ac, wcg[kb], bg, 0, 0, 0);
                bd = __builtin_amdgcn_mfma_f32_16x16x32_bf16(ac, wcd[kb], bd, 0, 0, 0);
            }
            floatx4 ag = {0.f, 0.f, 0.f, 0.f};
            floatx4 ad = {0.f, 0.f, 0.f, 0.f};
            floatx4 at = {0.f, 0.f, 0.f, 0.f};
            #pragma unroll
            for (int kb = 0; kb < 16; ++kb) {
                short8 a = *(const short8*)(AsL + kb * 512 + aoff);
                ag = __builtin_amdgcn_mfma_f32_16x16x32_bf16(a, wg[kb], ag, 0, 0, 0);
                ad = __builtin_amdgcn_mfma_f32_16x16x32_bf16(a, wd[kb], ad, 0, 0, 0);
                at = __builtin_amdgcn_mfma_f32_16x16x32_bf16(a, wt[kb], at, 0, 0, 0);
            }
            #pragma unroll
            for (int i = 0; i < 4; ++i) {
                baseg[i] = bg[i] + bgd_g;
                based[i] = bd[i] + bgd_d;
                float gate = ag[i] + baseg[i];
                float dyn = ad[i] + based[i];
                float tau = sp_(at[i] + btau);
                float ki = (sigm_(gate) * tanhf(dyn) - hreg[i]) / (tau + lk);
                rk1[i] = ki;
                float yn = hreg[i] + dt4[i] * ki * (1.f / 3.f);
                ycur[i] = yn;
                ypbuf[ypw + (quad * 4 + i) * 16] = f2bf_(yn);  // LDS transpose
            }
            __syncthreads();
            st64_((ull*)p.yapack + g * 2048 + j * 256 + tid,
                  ((const ull*)ypbuf)[tid]);   // coalesced 2 KB block burst
        }
        gsyncF(flags, j, ++cnt);

        // ---------- stages 2..4 ----------
        #pragma unroll 1
        for (int stage = 2; stage <= 4; ++stage) {
            const ull* src_qw = (stage == 2) ? ya_qw : (stage == 3) ? yb_qw : ya_qw;
            unsigned short* ydst =
                (stage == 2) ? p.ybpack : (stage == 3) ? p.yapack : p.hpack;
            {
                ull* dst = (ull*)AsL;
                #pragma unroll
                for (int i = 0; i < 8; ++i)
                    dst[tid + i * 256] = ld64_(src_qw + g * 2048 + tid + i * 256);
            }
            __syncthreads();
            floatx4 ag = {0.f, 0.f, 0.f, 0.f};
            floatx4 ad = {0.f, 0.f, 0.f, 0.f};
            floatx4 at = {0.f, 0.f, 0.f, 0.f};
            #pragma unroll
            for (int kb = 0; kb < 16; ++kb) {
                short8 a = *(const short8*)(AsL + kb * 512 + aoff);
                ag = __builtin_amdgcn_mfma_f32_16x16x32_bf16(a, wg[kb], ag, 0, 0, 0);
                ad = __builtin_amdgcn_mfma_f32_16x16x32_bf16(a, wd[kb], ad, 0, 0, 0);
                at = __builtin_amdgcn_mfma_f32_16x16x32_bf16(a, wt[kb], at, 0, 0, 0);
            }
            const int lane_p = ((c >> 3) & 3) * 16;
            #pragma unroll
            for (int i = 0; i < 4; ++i) {
                float gate = ag[i] + baseg[i];
                float dyn = ad[i] + based[i];
                float tau = sp_(at[i] + btau);
                float ki = (sigm_(gate) * tanhf(dyn) - ycur[i]) / (tau + lk);
                float yn;
                if (stage == 2) {
                    rk2[i] = ki;
                    yn = hreg[i] + dt4[i] * (ki - rk1[i] * (1.f / 3.f));
                } else if (stage == 3) {
                    rk3[i] = ki;
                    yn = hreg[i] + dt4[i] * (rk1[i] - rk2[i] + ki);
                } else {
                    yn = hreg[i] +
                         dt4[i] * (rk1[i] + 3.f * rk2[i] + 3.f * rk3[i] + ki) * 0.125f;
                    hreg[i] = yn;
                }
                ycur[i] = yn;
                ypbuf[ypw + (quad * 4 + i) * 16] = f2bf_(yn);
                if (stage == 4)
                    As2[(wave >> 1) * 512 + (c & 7) +
                        (lane_p + quad * 4 + i) * 8] = f2bf_(yn);
            }
            __syncthreads();
            st64_((ull*)ydst + g * 2048 + j * 256 + tid,
                  ((const ull*)ypbuf)[tid]);
            if (stage == 4) {
                // partial K/V over this block's K-range [j*64, j*64+64)
                #pragma unroll
                for (int h4 = 0; h4 < 4; ++h4) {
                    const int c4 = wave + h4 * 4;  // 0..15 (0..7=K, 8..15=V)
                    floatx4 acc = {0.f, 0.f, 0.f, 0.f};
                    #pragma unroll
                    for (int kk = 0; kk < 2; ++kk) {
                        short8 a = *(const short8*)(As2 + (kk * 64 + lane) * 8);
                        acc = __builtin_amdgcn_mfma_f32_16x16x32_bf16(
                            a, Wkv8[(c4 * 16 + (j * 2 + kk)) * 64 + lane], acc,
                            0, 0, 0);
                    }
                    const int ac = (c4 & 7) * 16 + (lane & 15);
                    float* part = (c4 < 8) ? p.Kpart : p.Vpart;
                    #pragma unroll
                    for (int i = 0; i < 4; ++i)
                        stf_(part + ((g * 8 + j) * 16 + quad * 4 + i) * 128 + ac,
                             acc[i]);
                }
            }
            gsyncF(flags, j, ++cnt);
        }
    }

    // ---------- write final h, then fc ----------
    #pragma unroll
    for (int i = 0; i < 4; ++i)
        stf_(p.h + (g * 16 + quad * 4 + i) * H_ + c, hreg[i]);
    gsyncF(flags, j, ++cnt);
    {
        const int o = tl & 31, ks = tl >> 5;  // ks 0..3
        float acc = 0.f;
        const float* hrow = p.h + r * H_ + ks * 128;
        const float* wcol = p.W_fc + ks * 128 * O_ + o;
        #pragma unroll 8
        for (int k = 0; k < 128; k += 2) {
            floatx2 hv = ldf2_(hrow + k);
            acc += hv.x * wcol[k * O_] + hv.y * wcol[(k + 1) * O_];
        }
        sc4[sub][tl] = acc;
        __syncthreads();
        if (ks == 0)
            p.out[r * O_ + o] = acc + sc4[sub][o + 32] + sc4[sub][o + 64] +
                                sc4[sub][o + 96] + p.b_fc[o];
    }
}

extern "C" void kernel_launch(void* const* d_in, const int* in_sizes, int n_in,
                              void* d_out, int out_size, void* d_ws,
                              size_t ws_size, hipStream_t stream) {
    (void)in_sizes; (void)n_in; (void)out_size; (void)ws_size;
    P p;
    p.x = (const float*)d_in[0];
    p.dts = (const float*)d_in[1];
    p.Wq = (const float*)d_in[2];
    p.bq = (const float*)d_in[3];
    const float* Wk = (const float*)d_in[4];
    p.bk = (const float*)d_in[5];
    const float* Wv = (const float*)d_in[6];
    p.bv = (const float*)d_in[7];
    const float* W_gd = (const float*)d_in[8];
    p.b_gd = (const float*)d_in[9];
    const float* W_tau = (const float*)d_in[10];
    p.b_tau = (const float*)d_in[11];
    p.gleak = (const float*)d_in[12];
    p.cm = (const float*)d_in[13];
    p.W_fc = (const float*)d_in[14];
    p.b_fc = (const float*)d_in[15];
    p.out = (float*)d_out;

    float* ws = (float*)d_ws;
    p.h = ws;                            // B*H fp32
    p.ctx = p.h + B_ * H_;               // B*A fp32
    p.Kpart = p.ctx + B_ * A_;           // 128*16*128 fp32
    p.Vpart = p.Kpart + 262144;
    unsigned short* Wpack = (unsigned short*)(p.Vpart + 262144);
    p.Wy = Wpack;                        // 786432 ushorts
    p.Wx = Wpack + 786432;               // 65536
    p.Wc = Wpack + 851968;               // 131072
    p.Wkv = Wpack + 983040;              // 131072
    p.hpack = Wpack + 1114112;           // B*H ushorts, strip-tile layout
    p.yapack = p.hpack + B_ * H_;
    p.ybpack = p.yapack + B_ * H_;
    p.Kh = p.ybpack + B_ * H_;           // B*T*A bf16 (block-private rows)
    p.bar = (unsigned*)(p.Kh + (size_t)B_ * T_ * A_);  // 8192 uints (flags)

    init_kernel<<<512, 256, 0, stream>>>(p.hpack, p.bar);
    pack_w_kernel<<<4352, 256, 0, stream>>>(W_gd, W_tau, Wk, Wv, Wpack);

    // 128 blocks x 256 threads, launch_bounds(256,1): 512-VGPR budget keeps
    // the 60 weight fragments register-resident. Exchange is now coalesced:
    // strip-tile pack layout, 8B system-scope bursts via LDS transpose, and
    // the V history lives entirely in LDS (block-private) — removes the 3x
    // scattered-store write amplification that dominated R8/R9's phase drain.
    fused_kernel<<<dim3(128), dim3(256), 0, stream>>>(p);
}

// Round 11
// 3570.049 us; speedup vs baseline: 3.4728x; 1.2974x over previous
//
#include <hip/hip_runtime.h>
#include <math.h>

#define B_ 256
#define T_ 128
#define D_ 64
#define H_ 512
#define A_ 128
#define O_ 32

typedef __attribute__((ext_vector_type(8))) short short8;
typedef __attribute__((ext_vector_type(8))) unsigned short ushort8;
typedef __attribute__((ext_vector_type(4))) float floatx4;
typedef __attribute__((ext_vector_type(4))) unsigned int uintx4;
typedef unsigned long long ull;

__device__ __forceinline__ float sp_(float x) {
    return fmaxf(x, 0.f) + log1pf(expf(-fabsf(x)));
}
__device__ __forceinline__ float sigm_(float x) {
    return 1.f / (1.f + expf(-x));
}
__device__ __forceinline__ unsigned short f2bf_(float f) {
    unsigned int u = __float_as_uint(f);
    return (unsigned short)((u + 0x7FFFu + ((u >> 16) & 1u)) >> 16);
}
__device__ __forceinline__ float bf2f_(unsigned short u) {
    return __uint_as_float(((unsigned)u) << 16);
}

// ---- raw MALL-coherent (sc0 sc1) loads, batched issue + single waitcnt -----
__device__ __forceinline__ void ld16sc(uintx4& d, const void* p) {
    asm volatile("global_load_dwordx4 %0, %1, off sc0 sc1"
                 : "=v"(d) : "v"(p) : "memory");
}
__device__ __forceinline__ void ld4sc(float& d, const void* p) {
    asm volatile("global_load_dword %0, %1, off sc0 sc1"
                 : "=v"(d) : "v"(p) : "memory");
}
__device__ __forceinline__ void vmwait4(uintx4& a, uintx4& b, uintx4& c,
                                        uintx4& d) {
    asm volatile("s_waitcnt vmcnt(0)"
                 : "+v"(a), "+v"(b), "+v"(c), "+v"(d)::"memory");
}
__device__ __forceinline__ void vmwait8(uintx4& a, uintx4& b, uintx4& c,
                                        uintx4& d, uintx4& e, uintx4& f,
                                        uintx4& g, uintx4& h) {
    asm volatile("s_waitcnt vmcnt(0)"
                 : "+v"(a), "+v"(b), "+v"(c), "+v"(d), "+v"(e), "+v"(f),
                   "+v"(g), "+v"(h)::"memory");
}
__device__ __forceinline__ void vmwait16f(float& a0, float& a1, float& a2,
                                          float& a3, float& a4, float& a5,
                                          float& a6, float& a7, float& b0,
                                          float& b1, float& b2, float& b3,
                                          float& b4, float& b5, float& b6,
                                          float& b7) {
    asm volatile("s_waitcnt vmcnt(0)"
                 : "+v"(a0), "+v"(a1), "+v"(a2), "+v"(a3), "+v"(a4), "+v"(a5),
                   "+v"(a6), "+v"(a7), "+v"(b0), "+v"(b1), "+v"(b2), "+v"(b3),
                   "+v"(b4), "+v"(b5), "+v"(b6), "+v"(b7)::"memory");
}
__device__ __forceinline__ floatx4 u2f_(uintx4 u) {
    union { uintx4 u; floatx4 f; } c;
    c.u = u;
    return c.f;
}

// ---- coherent store accessors (fire-and-forget, drained at barrier) --------
__device__ __forceinline__ void stf_(float* p, float v) {
    __hip_atomic_store(p, v, __ATOMIC_RELAXED, __HIP_MEMORY_SCOPE_SYSTEM);
}
__device__ __forceinline__ void st64_(ull* p, ull v) {
    __hip_atomic_store(p, v, __ATOMIC_RELAXED, __HIP_MEMORY_SCOPE_SYSTEM);
}

// ---------------- init: hpack = 0, flags = 0 --------------------------------
__global__ void init_kernel(unsigned short* __restrict__ hpack,
                            unsigned* __restrict__ bar) {
    int i = blockIdx.x * 256 + threadIdx.x;
    if (i < B_ * H_) hpack[i] = 0;
    if (i < 8192) bar[i] = 0u;
}

// -------- pack all weights into MFMA B-frag bf16 order ----------------------
__global__ void pack_w_kernel(const float* __restrict__ W_gd,
                              const float* __restrict__ W_tau,
                              const float* __restrict__ Wk,
                              const float* __restrict__ Wv,
                              unsigned short* __restrict__ Wpack) {
    int gid = blockIdx.x * 256 + threadIdx.x;
    if (gid >= 1114112) return;
    int j = gid & 7;
    int l = (gid >> 3) & 63;
    int kpart = (l >> 4) * 8 + j;
    int npart = l & 15;
    float v;
    if (gid < 786432) {
        int f = gid >> 9;
        int s = f % 3;
        int rem = f / 3;
        int kb = rem & 15, ct = rem >> 4;
        int k = kb * 32 + kpart;
        int c = ct * 16 + npart;
        if (s == 0)      v = W_gd[(size_t)(D_ + k) * 1024 + c];
        else if (s == 1) v = W_gd[(size_t)(D_ + k) * 1024 + 512 + c];
        else             v = W_tau[(size_t)k * 512 + c];
    } else if (gid < 851968) {
        int r = gid - 786432;
        int f = r >> 9;
        int s = f & 1, kb = (f >> 1) & 1, ct = f >> 2;
        int k = kb * 32 + kpart;
        int c = ct * 16 + npart;
        v = W_gd[(size_t)k * 1024 + s * 512 + c];
    } else if (gid < 983040) {
        int r = gid - 851968;
        int f = r >> 9;
        int s = f & 1, kb = (f >> 1) & 3, ct = f >> 3;
        int k = kb * 32 + kpart;
        int c = ct * 16 + npart;
        v = W_gd[(size_t)(D_ + H_ + k) * 1024 + s * 512 + c];
    } else {
        int r = gid - 983040;
        int f = r >> 9;
        int kb = f & 15, c4 = f >> 4;
        int k = kb * 32 + kpart;
        int n = (c4 & 7) * 16 + npart;
        v = (c4 < 8) ? Wk[(size_t)k * A_ + n] : Wv[(size_t)k * A_ + n];
    }
    Wpack[gid] = f2bf_(v);
}

// ---- group barrier: 8 blocks, per-block flag slots ----
__device__ __forceinline__ void gsyncF(unsigned* flags, int j, unsigned cnt) {
    asm volatile("s_waitcnt vmcnt(0)" ::: "memory");  // drain asm sc stores too
    __syncthreads();
    if (threadIdx.x == 0)
        __hip_atomic_store(flags + j * 64, cnt, __ATOMIC_RELAXED,
                           __HIP_MEMORY_SCOPE_SYSTEM);
    if (threadIdx.x < 8) {
        while (__hip_atomic_load(flags + threadIdx.x * 64, __ATOMIC_RELAXED,
                                 __HIP_MEMORY_SCOPE_SYSTEM) < cnt) {
            __builtin_amdgcn_s_sleep(1);
        }
    }
    __syncthreads();
}

struct P {
    const float *x, *dts, *Wq, *bq, *bk, *bv, *b_gd, *b_tau, *gleak, *cm,
        *W_fc, *b_fc;
    float *h, *ctx, *out, *Kpart, *Vpart;
    unsigned short* Kh;  // K: [B][T][A] bf16 (block-private rows, plain ld/st)
    const unsigned short *Wy, *Wx, *Wc, *Wkv;
    unsigned short *hpack, *yapack, *ybpack;  // layout [m_tile][strip][row][col]
    unsigned* bar;
};

__global__ __launch_bounds__(256, 1) void fused_kernel(P p) {
    const int tid = threadIdx.x;
    const int bid = blockIdx.x;
    const int lane = tid & 63;
    const int wave = tid >> 6;            // 0..3
    const int g = bid & 15;               // group of 8 blocks (bid%8 -> XCD)
    const int j = bid >> 4;               // block within group 0..7
    const int ct = j * 4 + wave;          // channel strip 0..31
    unsigned* flags = p.bar + g * 512;
    unsigned cnt = 0;

    __shared__ float WqL[D_ * 129];
    __shared__ float xs4[2][D_];
    __shared__ float q4[2][A_];
    __shared__ float sc4[2][T_];
    __shared__ float red[2][2];
    __shared__ __align__(16) unsigned short AsL[32 * 256];  // 16 KB staged A
    __shared__ __align__(16) unsigned short ypbuf[4 * 256]; // 2 KB transpose
    __shared__ __align__(16) unsigned short As2[2 * 512];   // kv h A-frags
    __shared__ unsigned short VhL[2][A_][136];              // ~70 KB V history

    const int quad = lane >> 4;
    const int c = ct * 16 + (lane & 15);
    const float btau = p.b_tau[c];
    const float lk = sp_(p.cm[c]) + sp_(p.gleak[c]) + 1e-6f;
    const float bgd_g = p.b_gd[c];
    const float bgd_d = p.b_gd[512 + c];
    const int aoff = (quad >> 1) * 256 + (lane & 15) * 16 + (quad & 1) * 8;
    const int ypw = wave * 256 + (lane & 15);

    const int sub = tid >> 7;             // 0..1
    const int tl = tid & 127;
    const int r = g * 16 + j * 2 + sub;   // this block's 2 attention rows
    const int rrow = r & 15;

    // ---- persistent register weights: 60 frags (240 VGPRs) ----
    short8 wg[16], wd[16], wt[16];
    short8 wxg[2], wxd[2], wcg[4], wcd[4];
    {
        const short8* Wy8 = (const short8*)p.Wy;
        #pragma unroll
        for (int kb = 0; kb < 16; ++kb) {
            wg[kb] = Wy8[((ct * 16 + kb) * 3 + 0) * 64 + lane];
            wd[kb] = Wy8[((ct * 16 + kb) * 3 + 1) * 64 + lane];
            wt[kb] = Wy8[((ct * 16 + kb) * 3 + 2) * 64 + lane];
        }
        const short8* Wx8 = (const short8*)p.Wx;
        const short8* Wc8 = (const short8*)p.Wc;
        #pragma unroll
        for (int kb = 0; kb < 2; ++kb) {
            wxg[kb] = Wx8[((ct * 2 + kb) * 2 + 0) * 64 + lane];
            wxd[kb] = Wx8[((ct * 2 + kb) * 2 + 1) * 64 + lane];
        }
        #pragma unroll
        for (int kb = 0; kb < 4; ++kb) {
            wcg[kb] = Wc8[((ct * 4 + kb) * 2 + 0) * 64 + lane];
            wcd[kb] = Wc8[((ct * 4 + kb) * 2 + 1) * 64 + lane];
        }
    }

    for (int i = tid; i < D_ * A_; i += 256) {
        int d = i >> 7, a = i & 127;
        WqL[d * 129 + a] = p.Wq[i];
    }

    floatx4 hreg = {0.f, 0.f, 0.f, 0.f};
    floatx4 rk1, rk2, rk3, baseg, based, ycur, dt4;

    const short8* Wkv8 = (const short8*)p.Wkv;

    __syncthreads();  // WqL ready

    for (int t = 0; t < T_; ++t) {
        // ---------- phase A: K/V merge of t-1 + attention (2 rows) ----------
        {
            if (t > 0) {
                // batched: issue all 16 sc loads, one waitcnt, then sum
                float kk[8], vv[8];
                #pragma unroll
                for (int jj = 0; jj < 8; ++jj) {
                    ld4sc(kk[jj],
                          p.Kpart + ((g * 8 + jj) * 16 + rrow) * 128 + tl);
                    ld4sc(vv[jj],
                          p.Vpart + ((g * 8 + jj) * 16 + rrow) * 128 + tl);
                }
                vmwait16f(kk[0], kk[1], kk[2], kk[3], kk[4], kk[5], kk[6],
                          kk[7], vv[0], vv[1], vv[2], vv[3], vv[4], vv[5],
                          vv[6], vv[7]);
                float ks = p.bk[tl], vs = p.bv[tl];
                #pragma unroll
                for (int jj = 0; jj < 8; ++jj) {
                    ks += kk[jj];
                    vs += vv[jj];
                }
                p.Kh[(size_t)(r * T_ + (t - 1)) * A_ + tl] = f2bf_(ks);
                VhL[sub][tl][t - 1] = f2bf_(vs);
            }
            if (tl < 16)
                ((float4*)xs4[sub])[tl] =
                    ((const float4*)&p.x[(r * T_ + t) * D_])[tl];
            __syncthreads();
            float qa = p.bq[tl];
            #pragma unroll 8
            for (int d = 0; d < D_; ++d) qa += xs4[sub][d] * WqL[d * 129 + tl];
            q4[sub][tl] = qa;
            __syncthreads();
            if (t == 0) {
                stf_(p.ctx + r * A_ + tl, 0.f);
            } else {
                const float rscale = 0.08838834764831845f;  // 1/sqrt(128)
                const int grp = tl >> 4, ln = tl & 15;
                float qv[8];
                #pragma unroll
                for (int i = 0; i < 8; ++i) qv[i] = q4[sub][ln * 8 + i];
                for (int s = grp; s < t; s += 8) {
                    ushort8 k8 = *((const ushort8*)(p.Kh +
                                     (size_t)(r * T_ + s) * A_) + ln);
                    float a2 = 0.f;
                    #pragma unroll
                    for (int i = 0; i < 8; ++i) a2 += bf2f_(k8[i]) * qv[i];
                    #pragma unroll
                    for (int off = 8; off > 0; off >>= 1)
                        a2 += __shfl_xor(a2, off, 16);
                    if (ln == 0) sc4[sub][s] = a2 * rscale;
                }
                __syncthreads();
                float mloc = -1e30f;
                for (int s = tl; s < t; s += 128) mloc = fmaxf(mloc, sc4[sub][s]);
                #pragma unroll
                for (int off = 32; off > 0; off >>= 1)
                    mloc = fmaxf(mloc, __shfl_xor(mloc, off, 64));
                if (lane == 0) red[sub][wave & 1] = mloc;
                __syncthreads();
                float m = fmaxf(red[sub][0], red[sub][1]);
                float ssum = 0.f;
                for (int s = tl; s < t; s += 128) {
                    float e = expf(sc4[sub][s] - m);
                    sc4[sub][s] = e;
                    ssum += e;
                }
                #pragma unroll
                for (int off = 32; off > 0; off >>= 1)
                    ssum += __shfl_xor(ssum, off, 64);
                __syncthreads();
                if (lane == 0) red[sub][wave & 1] = ssum;
                __syncthreads();
                float rs = 1.f / (red[sub][0] + red[sub][1]);
                const unsigned short* Vrow = &VhL[sub][tl][0];
                float ca0 = 0.f, ca1 = 0.f;
                int s0 = 0;
                for (; s0 + 16 <= t; s0 += 16) {
                    ushort8 v0 = *(const ushort8*)(Vrow + s0);
                    ushort8 v1 = *(const ushort8*)(Vrow + s0 + 8);
                    #pragma unroll
                    for (int i = 0; i < 8; ++i) {
                        ca0 += sc4[sub][s0 + i] * bf2f_(v0[i]);
                        ca1 += sc4[sub][s0 + 8 + i] * bf2f_(v1[i]);
                    }
                }
                if (s0 + 8 <= t) {
                    ushort8 v0 = *(const ushort8*)(Vrow + s0);
                    #pragma unroll
                    for (int i = 0; i < 8; ++i)
                        ca0 += sc4[sub][s0 + i] * bf2f_(v0[i]);
                    s0 += 8;
                }
                for (; s0 < t; ++s0) ca0 += sc4[sub][s0] * bf2f_(Vrow[s0]);
                stf_(p.ctx + r * A_ + tl, (ca0 + ca1) * rs);
            }
        }
        gsyncF(flags, j, ++cnt);

        // ---------- phase B: stage1 + base fold (register weights) ----------
        {
            // stage m_tile's hpack (16 KB) -> LDS: 4 batched 16B sc loads
            {
                const unsigned short* src = p.hpack + g * 8192;
                uintx4 av[4];
                #pragma unroll
                for (int i = 0; i < 4; ++i)
                    ld16sc(av[i], src + (size_t)tid * 8 + i * 2048);
                vmwait4(av[0], av[1], av[2], av[3]);
                #pragma unroll
                for (int i = 0; i < 4; ++i)
                    ((uintx4*)AsL)[tid + i * 256] = av[i];
            }
            // ctx row: 8 batched 16B sc loads
            const int mrow = lane & 15;
            const int kq = lane >> 4;
            const float* crow = &p.ctx[(g * 16 + mrow) * A_];
            uintx4 cc[8];
            #pragma unroll
            for (int kb = 0; kb < 4; ++kb) {
                ld16sc(cc[2 * kb], crow + kb * 32 + kq * 8);
                ld16sc(cc[2 * kb + 1], crow + kb * 32 + kq * 8 + 4);
            }
            vmwait8(cc[0], cc[1], cc[2], cc[3], cc[4], cc[5], cc[6], cc[7]);
            __syncthreads();  // AsL ready

            #pragma unroll
            for (int i = 0; i < 4; ++i)
                dt4[i] = p.dts[(g * 16 + quad * 4 + i) * T_ + t];

            floatx4 bg = {0.f, 0.f, 0.f, 0.f};
            floatx4 bd = {0.f, 0.f, 0.f, 0.f};
            const float4* xrow =
                (const float4*)&p.x[((g * 16 + mrow) * T_ + t) * D_];
            #pragma unroll
            for (int kb = 0; kb < 2; ++kb) {
                float4 u = xrow[kb * 8 + kq * 2], v = xrow[kb * 8 + kq * 2 + 1];
                short8 ax;
                ax[0] = (short)f2bf_(u.x); ax[1] = (short)f2bf_(u.y);
                ax[2] = (short)f2bf_(u.z); ax[3] = (short)f2bf_(u.w);
                ax[4] = (short)f2bf_(v.x); ax[5] = (short)f2bf_(v.y);
                ax[6] = (short)f2bf_(v.z); ax[7] = (short)f2bf_(v.w);
                bg = __builtin_amdgcn_mfma_f32_16x16x32_bf16(ax, wxg[kb], bg, 0, 0, 0);
                bd = __builtin_amdgcn_mfma_f32_16x16x32_bf16(ax, wxd[kb], bd, 0, 0, 0);
            }
            #pragma unroll
            for (int kb = 0; kb < 4; ++kb) {
                floatx4 f0 = u2f_(cc[2 * kb]), f1 = u2f_(cc[2 * kb + 1]);
                short8 ac;
                ac[0] = (short)f2bf_(f0[0]); ac[1] = (short)f2bf_(f0[1]);
                ac[2] = (short)f2bf_(f0[2]); ac[3] = (short)f2bf_(f0[3]);
                ac[4] = (short)f2bf_(f1[0]); ac[5] = (short)f2bf_(f1[1]);
                ac[6] = (short)f2bf_(f1[2]); ac[7] = (short)f2bf_(f1[3]);
                bg = __builtin_amdgcn_mfma_f32_16x16x32_bf16(ac, wcg[kb], bg, 0, 0, 0);
                bd = __builtin_amdgcn_mfma_f32_16x16x32_bf16(ac, wcd[kb], bd, 0, 0, 0);
            }
            floatx4 ag = {0.f, 0.f, 0.f, 0.f};
            floatx4 ad = {0.f, 0.f, 0.f, 0.f};
            floatx4 at = {0.f, 0.f, 0.f, 0.f};
            #pragma unroll
            for (int kb = 0; kb < 16; ++kb) {
                short8 a = *(const short8*)(AsL + kb * 512 + aoff);
                ag = __builtin_amdgcn_mfma_f32_16x16x32_bf16(a, wg[kb], ag, 0, 0, 0);
                ad = __builtin_amdgcn_mfma_f32_16x16x32_bf16(a, wd[kb], ad, 0, 0, 0);
                at = __builtin_amdgcn_mfma_f32_16x16x32_bf16(a, wt[kb], at, 0, 0, 0);
            }
            #pragma unroll
            for (int i = 0; i < 4; ++i) {
                baseg[i] = bg[i] + bgd_g;
                based[i] = bd[i] + bgd_d;
                float gate = ag[i] + baseg[i];
                float dyn = ad[i] + based[i];
                float tau = sp_(at[i] + btau);
                float ki = (sigm_(gate) * tanhf(dyn) - hreg[i]) / (tau + lk);
                rk1[i] = ki;
                float yn = hreg[i] + dt4[i] * ki * (1.f / 3.f);
                ycur[i] = yn;
                ypbuf[ypw + (quad * 4 + i) * 16] = f2bf_(yn);
            }
            __syncthreads();
            st64_((ull*)p.yapack + g * 2048 + j * 256 + tid,
                  ((const ull*)ypbuf)[tid]);
        }
        gsyncF(flags, j, ++cnt);

        // ---------- stages 2..4 ----------
        #pragma unroll 1
        for (int stage = 2; stage <= 4; ++stage) {
            const unsigned short* ysrc =
                (stage == 2) ? p.yapack : (stage == 3) ? p.ybpack : p.yapack;
            unsigned short* ydst =
                (stage == 2) ? p.ybpack : (stage == 3) ? p.yapack : p.hpack;
            {
                const unsigned short* src = ysrc + g * 8192;
                uintx4 av[4];
                #pragma unroll
                for (int i = 0; i < 4; ++i)
                    ld16sc(av[i], src + (size_t)tid * 8 + i * 2048);
                vmwait4(av[0], av[1], av[2], av[3]);
                #pragma unroll
                for (int i = 0; i < 4; ++i)
                    ((uintx4*)AsL)[tid + i * 256] = av[i];
            }
            __syncthreads();
            floatx4 ag = {0.f, 0.f, 0.f, 0.f};
            floatx4 ad = {0.f, 0.f, 0.f, 0.f};
            floatx4 at = {0.f, 0.f, 0.f, 0.f};
            #pragma unroll
            for (int kb = 0; kb < 16; ++kb) {
                short8 a = *(const short8*)(AsL + kb * 512 + aoff);
                ag = __builtin_amdgcn_mfma_f32_16x16x32_bf16(a, wg[kb], ag, 0, 0, 0);
                ad = __builtin_amdgcn_mfma_f32_16x16x32_bf16(a, wd[kb], ad, 0, 0, 0);
                at = __builtin_amdgcn_mfma_f32_16x16x32_bf16(a, wt[kb], at, 0, 0, 0);
            }
            const int lane_p = ((c >> 3) & 3) * 16;
            #pragma unroll
            for (int i = 0; i < 4; ++i) {
                float gate = ag[i] + baseg[i];
                float dyn = ad[i] + based[i];
                float tau = sp_(at[i] + btau);
                float ki = (sigm_(gate) * tanhf(dyn) - ycur[i]) / (tau + lk);
                float yn;
                if (stage == 2) {
                    rk2[i] = ki;
                    yn = hreg[i] + dt4[i] * (ki - rk1[i] * (1.f / 3.f));
                } else if (stage == 3) {
                    rk3[i] = ki;
                    yn = hreg[i] + dt4[i] * (rk1[i] - rk2[i] + ki);
                } else {
                    yn = hreg[i] +
                         dt4[i] * (rk1[i] + 3.f * rk2[i] + 3.f * rk3[i] + ki) * 0.125f;
                    hreg[i] = yn;
                }
                ycur[i] = yn;
                ypbuf[ypw + (quad * 4 + i) * 16] = f2bf_(yn);
                if (stage == 4)
                    As2[(wave >> 1) * 512 + (c & 7) +
                        (lane_p + quad * 4 + i) * 8] = f2bf_(yn);
            }
            __syncthreads();
            st64_((ull*)ydst + g * 2048 + j * 256 + tid,
                  ((const ull*)ypbuf)[tid]);
            if (stage == 4) {
                #pragma unroll
                for (int h4 = 0; h4 < 4; ++h4) {
                    const int c4 = wave + h4 * 4;  // 0..15 (0..7=K, 8..15=V)
                    floatx4 acc = {0.f, 0.f, 0.f, 0.f};
                    #pragma unroll
                    for (int kk2 = 0; kk2 < 2; ++kk2) {
                        short8 a = *(const short8*)(As2 + (kk2 * 64 + lane) * 8);
                        acc = __builtin_amdgcn_mfma_f32_16x16x32_bf16(
                            a, Wkv8[(c4 * 16 + (j * 2 + kk2)) * 64 + lane], acc,
                            0, 0, 0);
                    }
                    const int ac = (c4 & 7) * 16 + (lane & 15);
                    float* part = (c4 < 8) ? p.Kpart : p.Vpart;
                    #pragma unroll
                    for (int i = 0; i < 4; ++i)
                        stf_(part + ((g * 8 + j) * 16 + quad * 4 + i) * 128 + ac,
                             acc[i]);
                }
            }
            gsyncF(flags, j, ++cnt);
        }
    }

    // ---------- write final h, then fc ----------
    #pragma unroll
    for (int i = 0; i < 4; ++i)
        stf_(p.h + (g * 16 + quad * 4 + i) * H_ + c, hreg[i]);
    gsyncF(flags, j, ++cnt);
    {
        const int o = tl & 31, ks = tl >> 5;  // ks 0..3
        float acc = 0.f;
        const float* hrow = p.h + r * H_ + ks * 128;
        const float* wcol = p.W_fc + ks * 128 * O_ + o;
        #pragma unroll 1
        for (int rd = 0; rd < 4; ++rd) {
            uintx4 hh[8];
            #pragma unroll
            for (int i = 0; i < 8; ++i)
                ld16sc(hh[i], hrow + rd * 32 + i * 4);
            vmwait8(hh[0], hh[1], hh[2], hh[3], hh[4], hh[5], hh[6], hh[7]);
            #pragma unroll
            for (int i = 0; i < 8; ++i) {
                floatx4 f = u2f_(hh[i]);
                #pragma unroll
                for (int e = 0; e < 4; ++e)
                    acc += f[e] * wcol[(rd * 32 + i * 4 + e) * O_];
            }
        }
        sc4[sub][tl] = acc;
        __syncthreads();
        if (ks == 0)
            p.out[r * O_ + o] = acc + sc4[sub][o + 32] + sc4[sub][o + 64] +
                                sc4[sub][o + 96] + p.b_fc[o];
    }
}

extern "C" void kernel_launch(void* const* d_in, const int* in_sizes, int n_in,
                              void* d_out, int out_size, void* d_ws,
                              size_t ws_size, hipStream_t stream) {
    (void)in_sizes; (void)n_in; (void)out_size; (void)ws_size;
    P p;
    p.x = (const float*)d_in[0];
    p.dts = (const float*)d_in[1];
    p.Wq = (const float*)d_in[2];
    p.bq = (const float*)d_in[3];
    const float* Wk = (const float*)d_in[4];
    p.bk = (const float*)d_in[5];
    const float* Wv = (const float*)d_in[6];
    p.bv = (const float*)d_in[7];
    const float* W_gd = (const float*)d_in[8];
    p.b_gd = (const float*)d_in[9];
    const float* W_tau = (const float*)d_in[10];
    p.b_tau = (const float*)d_in[11];
    p.gleak = (const float*)d_in[12];
    p.cm = (const float*)d_in[13];
    p.W_fc = (const float*)d_in[14];
    p.b_fc = (const float*)d_in[15];
    p.out = (float*)d_out;

    float* ws = (float*)d_ws;
    p.h = ws;                            // B*H fp32
    p.ctx = p.h + B_ * H_;               // B*A fp32
    p.Kpart = p.ctx + B_ * A_;           // 128*16*128 fp32
    p.Vpart = p.Kpart + 262144;
    unsigned short* Wpack = (unsigned short*)(p.Vpart + 262144);
    p.Wy = Wpack;                        // 786432 ushorts
    p.Wx = Wpack + 786432;               // 65536
    p.Wc = Wpack + 851968;               // 131072
    p.Wkv = Wpack + 983040;              // 131072
    p.hpack = Wpack + 1114112;           // B*H ushorts, strip-tile layout
    p.yapack = p.hpack + B_ * H_;
    p.ybpack = p.yapack + B_ * H_;
    p.Kh = p.ybpack + B_ * H_;           // B*T*A bf16 (block-private rows)
    p.bar = (unsigned*)(p.Kh + (size_t)B_ * T_ * A_);  // 8192 uints (flags)

    init_kernel<<<512, 256, 0, stream>>>(p.hpack, p.bar);
    pack_w_kernel<<<4352, 256, 0, stream>>>(W_gd, W_tau, Wk, Wv, Wpack);

    // 128 blocks x 256 threads, launch_bounds(256,1). R11 change: all hot-path
    // cross-block loads are raw inline-asm `global_load sc0 sc1` issued in
    // batches with ONE operand-tied s_waitcnt — the HIP atomic-load path
    // emitted a serial waitcnt per load, making every exchange a chain of
    // ~900-cycle MALL round trips (the R8-R10 ~7us/phase floor).
    fused_kernel<<<dim3(128), dim3(256), 0, stream>>>(p);
}